// Round 1
// baseline (6581.180 us; speedup 1.0000x reference)
//
#include <hip/hip_runtime.h>
#include <cstddef>
#include <cstdint>

#define Bn 4
#define Tn 2048
#define Cn 768
#define Hn 12
#define Dn 64

// ---------------- fp32 GEMM: C = A(MxK) @ B(KxN), 64x64 tile, BK=16 ----------------
__global__ __launch_bounds__(256) void gemm_f32_64(
    const float* __restrict__ A, const float* __restrict__ B,
    float* __restrict__ C, int M, int N, int K) {
  __shared__ float As[16][68];  // [k][m], pad to 68 for bank spread + 16B align
  __shared__ float Bs[16][68];  // [k][n]
  const int bm = blockIdx.y * 64;
  const int bn = blockIdx.x * 64;
  const int tid = threadIdx.x;
  const int tr = (tid >> 4) << 2;   // 0..60 step 4
  const int tc = (tid & 15) << 2;   // 0..60 step 4

  const int mA  = tid >> 2;          // 0..63
  const int kqA = (tid & 3) << 2;    // 0,4,8,12
  const int kB  = tid >> 4;          // 0..15
  const int nqB = (tid & 15) << 2;   // 0..60

  float acc[4][4] = {};

  for (int k0 = 0; k0 < K; k0 += 16) {
    float4 av = *reinterpret_cast<const float4*>(&A[(size_t)(bm + mA) * K + k0 + kqA]);
    float4 bv = *reinterpret_cast<const float4*>(&B[(size_t)(k0 + kB) * N + bn + nqB]);
    As[kqA + 0][mA] = av.x;
    As[kqA + 1][mA] = av.y;
    As[kqA + 2][mA] = av.z;
    As[kqA + 3][mA] = av.w;
    *reinterpret_cast<float4*>(&Bs[kB][nqB]) = bv;
    __syncthreads();
    #pragma unroll
    for (int k = 0; k < 16; ++k) {
      float a0 = As[k][tr + 0], a1 = As[k][tr + 1], a2 = As[k][tr + 2], a3 = As[k][tr + 3];
      float b0 = Bs[k][tc + 0], b1 = Bs[k][tc + 1], b2 = Bs[k][tc + 2], b3 = Bs[k][tc + 3];
      acc[0][0] = fmaf(a0, b0, acc[0][0]);
      acc[0][1] = fmaf(a0, b1, acc[0][1]);
      acc[0][2] = fmaf(a0, b2, acc[0][2]);
      acc[0][3] = fmaf(a0, b3, acc[0][3]);
      acc[1][0] = fmaf(a1, b0, acc[1][0]);
      acc[1][1] = fmaf(a1, b1, acc[1][1]);
      acc[1][2] = fmaf(a1, b2, acc[1][2]);
      acc[1][3] = fmaf(a1, b3, acc[1][3]);
      acc[2][0] = fmaf(a2, b0, acc[2][0]);
      acc[2][1] = fmaf(a2, b1, acc[2][1]);
      acc[2][2] = fmaf(a2, b2, acc[2][2]);
      acc[2][3] = fmaf(a2, b3, acc[2][3]);
      acc[3][0] = fmaf(a3, b0, acc[3][0]);
      acc[3][1] = fmaf(a3, b1, acc[3][1]);
      acc[3][2] = fmaf(a3, b2, acc[3][2]);
      acc[3][3] = fmaf(a3, b3, acc[3][3]);
    }
    __syncthreads();
  }

  #pragma unroll
  for (int i = 0; i < 4; ++i) {
    float4 o = make_float4(acc[i][0], acc[i][1], acc[i][2], acc[i][3]);
    *reinterpret_cast<float4*>(&C[(size_t)(bm + tr + i) * N + bn + tc]) = o;
  }
}

// ---------------- fused causal relu-attention ----------------
// qkv: (B, T, 3C) fp32.  q = qkv[b][t][h*64+d], k at +C, v at +2C.
// out: (B, T, C) fp32 (already head-merged layout).
// scores = (q.k / 8) * (1 + lambda_h * log(q+1)); relu; * causal * attn_mask[k];
// weights = att / (rowsum + 1e-9); out = weights @ v.
__global__ __launch_bounds__(256) void attn_kernel(
    const float* __restrict__ qkv, const float* __restrict__ attn_mask,
    const float* __restrict__ lambda, float* __restrict__ out) {
  const int blk = blockIdx.x;                 // b*H*32 + h*32 + qt
  const int qt = blk & 31;
  const int h  = (blk >> 5) % Hn;
  const int b  = blk / (32 * Hn);
  const int tid  = threadIdx.x;
  const int w    = tid >> 6;                  // wave 0..3
  const int lane = tid & 63;

  __shared__ float q_lds[64][Dn + 1];
  __shared__ float k_lds[64][Dn + 1];
  __shared__ float v_lds[64][Dn + 1];
  __shared__ float mk[64];

  const float inv = 0.125f;                   // 1/sqrt(64)
  const float lam = lambda[h];
  const int qbase = qt * 64;
  const float* base = qkv + (size_t)b * Tn * 3 * Cn;

  // load q tile (pre-scaled by 1/sqrt(D))
  for (int i = tid; i < 64 * 64; i += 256) {
    int r = i >> 6, d = i & 63;
    q_lds[r][d] = base[(size_t)(qbase + r) * (3 * Cn) + h * 64 + d] * inv;
  }

  float accd[16];
  float den[16];
  #pragma unroll
  for (int r = 0; r < 16; ++r) { accd[r] = 0.f; den[r] = 0.f; }

  // row scales for this wave's 16 rows
  float rowscale[16];
  #pragma unroll
  for (int r = 0; r < 16; ++r) {
    int qrow = qbase + w * 16 + r;
    rowscale[r] = 1.0f + lam * logf((float)qrow + 1.0f);
  }

  const int nkt = qt + 1;
  for (int kt = 0; kt < nkt; ++kt) {
    __syncthreads();
    for (int i = tid; i < 64 * 64; i += 256) {
      int r = i >> 6, d = i & 63;
      size_t row = (size_t)(kt * 64 + r) * (3 * Cn);
      k_lds[r][d] = base[row + Cn + h * 64 + d];
      v_lds[r][d] = base[row + 2 * Cn + h * 64 + d];
    }
    if (tid < 64) mk[tid] = attn_mask[b * Tn + kt * 64 + tid];
    __syncthreads();

    for (int r = 0; r < 16; ++r) {
      const int qrow = qbase + w * 16 + r;
      const int krow = kt * 64 + lane;
      float s = 0.f;
      #pragma unroll
      for (int d = 0; d < 64; ++d) s = fmaf(q_lds[w * 16 + r][d], k_lds[lane][d], s);
      s *= rowscale[r];
      s = (krow <= qrow) ? fmaxf(s, 0.f) * mk[lane] : 0.f;
      const int kkmax = min(63, qrow - kt * 64);
      float a = accd[r], dn = den[r];
      for (int kk = 0; kk <= kkmax; ++kk) {
        float sv = __shfl(s, kk);
        a  = fmaf(sv, v_lds[kk][lane], a);
        dn += sv;
      }
      accd[r] = a; den[r] = dn;
    }
  }

  float* optr = out + (size_t)b * Tn * Cn;
  #pragma unroll
  for (int r = 0; r < 16; ++r) {
    int qrow = qbase + w * 16 + r;
    optr[(size_t)qrow * Cn + h * 64 + lane] = accd[r] / (den[r] + 1e-9f);
  }
}

extern "C" void kernel_launch(void* const* d_in, const int* in_sizes, int n_in,
                              void* d_out, int out_size, void* d_ws, size_t ws_size,
                              hipStream_t stream) {
  const float* x         = (const float*)d_in[0];  // (B,T,C)
  const float* attn_mask = (const float*)d_in[1];  // (B,T)
  const float* lambda    = (const float*)d_in[2];  // (H,)
  const float* W_attn    = (const float*)d_in[3];  // (C,3C)
  const float* W_proj    = (const float*)d_in[4];  // (C,C)
  float* out = (float*)d_out;

  float* qkv      = (float*)d_ws;                         // B*T*3C
  float* attn_out = qkv + (size_t)Bn * Tn * 3 * Cn;       // B*T*C

  dim3 blk(256);

  // qkv = x @ W_attn : M=8192, N=2304, K=768
  gemm_f32_64<<<dim3((3 * Cn) / 64, (Bn * Tn) / 64), blk, 0, stream>>>(
      x, W_attn, qkv, Bn * Tn, 3 * Cn, Cn);

  // fused attention
  attn_kernel<<<dim3(Bn * Hn * (Tn / 64)), blk, 0, stream>>>(
      qkv, attn_mask, lambda, attn_out);

  // out = attn_out @ W_proj : M=8192, N=768, K=768
  gemm_f32_64<<<dim3(Cn / 64, (Bn * Tn) / 64), blk, 0, stream>>>(
      attn_out, W_proj, out, Bn * Tn, Cn, Cn);
}

// Round 2
// 662.095 us; speedup vs baseline: 9.9399x; 9.9399x over previous
//
#include <hip/hip_runtime.h>
#include <cstddef>
#include <cstdint>

#define Bn 4
#define Tn 2048
#define Cn 768
#define Hn 12
#define Dn 64

typedef __attribute__((ext_vector_type(8))) short short8v;
typedef __attribute__((ext_vector_type(4))) float f32x4;

struct us4 { unsigned short x, y, z, w; };

__device__ inline unsigned short f2bf(float f) {
  union { float f; unsigned u; } v; v.f = f;
  unsigned r = v.u + 0x7FFFu + ((v.u >> 16) & 1u);
  return (unsigned short)(r >> 16);
}

// ---------------- fp32 GEMM (proj): C = A(MxK) @ B(KxN), 64x64 tile ----------------
__global__ __launch_bounds__(256) void gemm_f32_64(
    const float* __restrict__ A, const float* __restrict__ B,
    float* __restrict__ C, int M, int N, int K) {
  __shared__ float As[16][68];
  __shared__ float Bs[16][68];
  const int bm = blockIdx.y * 64;
  const int bn = blockIdx.x * 64;
  const int tid = threadIdx.x;
  const int tr = (tid >> 4) << 2;
  const int tc = (tid & 15) << 2;
  const int mA  = tid >> 2;
  const int kqA = (tid & 3) << 2;
  const int kB  = tid >> 4;
  const int nqB = (tid & 15) << 2;

  float acc[4][4] = {};
  for (int k0 = 0; k0 < K; k0 += 16) {
    float4 av = *reinterpret_cast<const float4*>(&A[(size_t)(bm + mA) * K + k0 + kqA]);
    float4 bv = *reinterpret_cast<const float4*>(&B[(size_t)(k0 + kB) * N + bn + nqB]);
    As[kqA + 0][mA] = av.x; As[kqA + 1][mA] = av.y;
    As[kqA + 2][mA] = av.z; As[kqA + 3][mA] = av.w;
    *reinterpret_cast<float4*>(&Bs[kB][nqB]) = bv;
    __syncthreads();
    #pragma unroll
    for (int k = 0; k < 16; ++k) {
      float a0 = As[k][tr + 0], a1 = As[k][tr + 1], a2 = As[k][tr + 2], a3 = As[k][tr + 3];
      float b0 = Bs[k][tc + 0], b1 = Bs[k][tc + 1], b2 = Bs[k][tc + 2], b3 = Bs[k][tc + 3];
      acc[0][0] = fmaf(a0, b0, acc[0][0]); acc[0][1] = fmaf(a0, b1, acc[0][1]);
      acc[0][2] = fmaf(a0, b2, acc[0][2]); acc[0][3] = fmaf(a0, b3, acc[0][3]);
      acc[1][0] = fmaf(a1, b0, acc[1][0]); acc[1][1] = fmaf(a1, b1, acc[1][1]);
      acc[1][2] = fmaf(a1, b2, acc[1][2]); acc[1][3] = fmaf(a1, b3, acc[1][3]);
      acc[2][0] = fmaf(a2, b0, acc[2][0]); acc[2][1] = fmaf(a2, b1, acc[2][1]);
      acc[2][2] = fmaf(a2, b2, acc[2][2]); acc[2][3] = fmaf(a2, b3, acc[2][3]);
      acc[3][0] = fmaf(a3, b0, acc[3][0]); acc[3][1] = fmaf(a3, b1, acc[3][1]);
      acc[3][2] = fmaf(a3, b2, acc[3][2]); acc[3][3] = fmaf(a3, b3, acc[3][3]);
    }
    __syncthreads();
  }
  #pragma unroll
  for (int i = 0; i < 4; ++i) {
    float4 o = make_float4(acc[i][0], acc[i][1], acc[i][2], acc[i][3]);
    *reinterpret_cast<float4*>(&C[(size_t)(bm + tr + i) * N + bn + tc]) = o;
  }
}

// ---------------- qkv GEMM with fused bf16 split/scale/transpose epilogue --------
// q -> qb [B*H][T][64] bf16, pre-scaled by 0.125*(1+lambda_h*log(t+1))
// k -> kb [B*H][T][64] bf16
// v -> vt [B*H][64][T] bf16 (transposed)
__global__ __launch_bounds__(256) void gemm_qkv(
    const float* __restrict__ A, const float* __restrict__ B,
    const float* __restrict__ lambda,
    unsigned short* __restrict__ qb, unsigned short* __restrict__ kb,
    unsigned short* __restrict__ vt) {
  const int M = Bn * Tn, N = 3 * Cn, K = Cn;
  __shared__ float As[16][68];
  __shared__ float Bs[16][68];
  const int bm = blockIdx.y * 64;
  const int bn = blockIdx.x * 64;
  const int tid = threadIdx.x;
  const int tr = (tid >> 4) << 2;
  const int tc = (tid & 15) << 2;
  const int mA  = tid >> 2;
  const int kqA = (tid & 3) << 2;
  const int kB  = tid >> 4;
  const int nqB = (tid & 15) << 2;

  float acc[4][4] = {};
  for (int k0 = 0; k0 < K; k0 += 16) {
    float4 av = *reinterpret_cast<const float4*>(&A[(size_t)(bm + mA) * K + k0 + kqA]);
    float4 bv = *reinterpret_cast<const float4*>(&B[(size_t)(k0 + kB) * N + bn + nqB]);
    As[kqA + 0][mA] = av.x; As[kqA + 1][mA] = av.y;
    As[kqA + 2][mA] = av.z; As[kqA + 3][mA] = av.w;
    *reinterpret_cast<float4*>(&Bs[kB][nqB]) = bv;
    __syncthreads();
    #pragma unroll
    for (int k = 0; k < 16; ++k) {
      float a0 = As[k][tr + 0], a1 = As[k][tr + 1], a2 = As[k][tr + 2], a3 = As[k][tr + 3];
      float b0 = Bs[k][tc + 0], b1 = Bs[k][tc + 1], b2 = Bs[k][tc + 2], b3 = Bs[k][tc + 3];
      acc[0][0] = fmaf(a0, b0, acc[0][0]); acc[0][1] = fmaf(a0, b1, acc[0][1]);
      acc[0][2] = fmaf(a0, b2, acc[0][2]); acc[0][3] = fmaf(a0, b3, acc[0][3]);
      acc[1][0] = fmaf(a1, b0, acc[1][0]); acc[1][1] = fmaf(a1, b1, acc[1][1]);
      acc[1][2] = fmaf(a1, b2, acc[1][2]); acc[1][3] = fmaf(a1, b3, acc[1][3]);
      acc[2][0] = fmaf(a2, b0, acc[2][0]); acc[2][1] = fmaf(a2, b1, acc[2][1]);
      acc[2][2] = fmaf(a2, b2, acc[2][2]); acc[2][3] = fmaf(a2, b3, acc[2][3]);
      acc[3][0] = fmaf(a3, b0, acc[3][0]); acc[3][1] = fmaf(a3, b1, acc[3][1]);
      acc[3][2] = fmaf(a3, b2, acc[3][2]); acc[3][3] = fmaf(a3, b3, acc[3][3]);
    }
    __syncthreads();
  }

  // epilogue: bn is 64-aligned, 768 % 64 == 0 -> segment and head uniform per block
  const int seg = bn / Cn;               // 0=q, 1=k, 2=v
  const int h   = (bn - seg * Cn) >> 6;  // uniform over block
  const float lam = lambda[h];
  #pragma unroll
  for (int i = 0; i < 4; ++i) {
    const int m = bm + tr + i;
    const int b = m >> 11;          // T=2048
    const int t = m & (Tn - 1);
    const size_t bh = (size_t)(b * Hn + h);
    if (seg == 0) {
      float sc = 0.125f * (1.0f + lam * logf((float)t + 1.0f));
      us4 p;
      p.x = f2bf(acc[i][0] * sc); p.y = f2bf(acc[i][1] * sc);
      p.z = f2bf(acc[i][2] * sc); p.w = f2bf(acc[i][3] * sc);
      *reinterpret_cast<us4*>(&qb[(bh * Tn + t) * 64 + tc]) = p;
    } else if (seg == 1) {
      us4 p;
      p.x = f2bf(acc[i][0]); p.y = f2bf(acc[i][1]);
      p.z = f2bf(acc[i][2]); p.w = f2bf(acc[i][3]);
      *reinterpret_cast<us4*>(&kb[(bh * Tn + t) * 64 + tc]) = p;
    } else {
      #pragma unroll
      for (int j = 0; j < 4; ++j)
        vt[(bh * 64 + tc + j) * Tn + t] = f2bf(acc[i][j]);
    }
  }
}

// ---------------- MFMA flash-style relu-attention ----------------
// Per block: 64 q rows (4 waves x 16). num/den accumulation, no softmax max.
__global__ __launch_bounds__(256) void attn_mfma(
    const unsigned short* __restrict__ qb, const unsigned short* __restrict__ kb,
    const unsigned short* __restrict__ vt, const float* __restrict__ attn_mask,
    float* __restrict__ out) {
  const int qt = blockIdx.x & 31;
  const int bh = blockIdx.x >> 5;
  const int b = bh / Hn, h = bh % Hn;
  const int tid = threadIdx.x;
  const int w = tid >> 6;
  const int lane = tid & 63;
  const int lcol = lane & 15;
  const int g = lane >> 4;

  __shared__ unsigned short K_lds[64][72];   // [k][d], padded
  __shared__ unsigned short V_lds[64][72];   // [d][k], padded (V transposed)
  __shared__ unsigned short P_lds[4][16][72];
  __shared__ float mk[64];

  // Q fragments: rows w*16 + lcol, k-chunks d0=0 and 32
  const unsigned short* qrow = qb + ((size_t)bh * Tn + qt * 64 + w * 16 + lcol) * 64;
  short8v qf0 = *reinterpret_cast<const short8v*>(qrow + g * 8);
  short8v qf1 = *reinterpret_cast<const short8v*>(qrow + 32 + g * 8);

  f32x4 o[4];
  #pragma unroll
  for (int dt = 0; dt < 4; ++dt) o[dt] = (f32x4){0.f, 0.f, 0.f, 0.f};
  float dsum[4] = {0.f, 0.f, 0.f, 0.f};

  const int nkt = qt + 1;
  for (int kt = 0; kt < nkt; ++kt) {
    __syncthreads();
    {
      const unsigned short* ks = kb + ((size_t)bh * Tn + kt * 64) * 64;
      const unsigned short* vs = vt + (size_t)bh * 64 * Tn + kt * 64;
      #pragma unroll
      for (int it = 0; it < 2; ++it) {
        int s = tid + it * 256;
        int r = s >> 3, c8 = (s & 7) * 8;
        *reinterpret_cast<short8v*>(&K_lds[r][c8]) =
            *reinterpret_cast<const short8v*>(ks + r * 64 + c8);
        *reinterpret_cast<short8v*>(&V_lds[r][c8]) =
            *reinterpret_cast<const short8v*>(vs + (size_t)r * Tn + c8);
      }
      if (tid < 64) mk[tid] = attn_mask[b * Tn + kt * 64 + tid];
    }
    __syncthreads();

    const bool diag = (kt == qt);
    #pragma unroll
    for (int c = 0; c < 4; ++c) {
      f32x4 s = (f32x4){0.f, 0.f, 0.f, 0.f};
      short8v kf0 = *reinterpret_cast<const short8v*>(&K_lds[c * 16 + lcol][g * 8]);
      short8v kf1 = *reinterpret_cast<const short8v*>(&K_lds[c * 16 + lcol][32 + g * 8]);
      s = __builtin_amdgcn_mfma_f32_16x16x32_bf16(qf0, kf0, s, 0, 0, 0);
      s = __builtin_amdgcn_mfma_f32_16x16x32_bf16(qf1, kf1, s, 0, 0, 0);
      const float m = mk[c * 16 + lcol];
      #pragma unroll
      for (int r = 0; r < 4; ++r) {
        float sv = fmaxf(s[r], 0.f) * m;
        if (diag) {
          int qr = w * 16 + g * 4 + r;
          int kr = c * 16 + lcol;
          if (kr > qr) sv = 0.f;
        }
        dsum[r] += sv;
        P_lds[w][g * 4 + r][c * 16 + lcol] = f2bf(sv);
      }
    }
    __syncthreads();

    short8v pf0 = *reinterpret_cast<const short8v*>(&P_lds[w][lcol][g * 8]);
    short8v pf1 = *reinterpret_cast<const short8v*>(&P_lds[w][lcol][32 + g * 8]);
    #pragma unroll
    for (int dt = 0; dt < 4; ++dt) {
      short8v vf0 = *reinterpret_cast<const short8v*>(&V_lds[dt * 16 + lcol][g * 8]);
      short8v vf1 = *reinterpret_cast<const short8v*>(&V_lds[dt * 16 + lcol][32 + g * 8]);
      o[dt] = __builtin_amdgcn_mfma_f32_16x16x32_bf16(pf0, vf0, o[dt], 0, 0, 0);
      o[dt] = __builtin_amdgcn_mfma_f32_16x16x32_bf16(pf1, vf1, o[dt], 0, 0, 0);
    }
  }

  #pragma unroll
  for (int r = 0; r < 4; ++r) {
    float d = dsum[r];
    d += __shfl_xor(d, 1); d += __shfl_xor(d, 2);
    d += __shfl_xor(d, 4); d += __shfl_xor(d, 8);
    dsum[r] = 1.0f / (d + 1e-9f);
  }
  float* ob = out + ((size_t)b * Tn + qt * 64 + w * 16) * Cn + h * 64;
  #pragma unroll
  for (int dt = 0; dt < 4; ++dt)
    #pragma unroll
    for (int r = 0; r < 4; ++r)
      ob[(size_t)(g * 4 + r) * Cn + dt * 16 + lcol] = o[dt][r] * dsum[r];
}

extern "C" void kernel_launch(void* const* d_in, const int* in_sizes, int n_in,
                              void* d_out, int out_size, void* d_ws, size_t ws_size,
                              hipStream_t stream) {
  const float* x         = (const float*)d_in[0];
  const float* attn_mask = (const float*)d_in[1];
  const float* lambda    = (const float*)d_in[2];
  const float* W_attn    = (const float*)d_in[3];
  const float* W_proj    = (const float*)d_in[4];
  float* out = (float*)d_out;

  const size_t nBHTD = (size_t)Bn * Hn * Tn * 64;  // 6.29M elements
  unsigned short* qb = (unsigned short*)d_ws;
  unsigned short* kb = qb + nBHTD;
  unsigned short* vt = kb + nBHTD;
  float* attn_out = (float*)(vt + nBHTD);          // B*T*C fp32

  dim3 blk(256);

  gemm_qkv<<<dim3((3 * Cn) / 64, (Bn * Tn) / 64), blk, 0, stream>>>(
      x, W_attn, lambda, qb, kb, vt);

  attn_mfma<<<dim3(Bn * Hn * (Tn / 64)), blk, 0, stream>>>(
      qb, kb, vt, attn_mask, attn_out);

  gemm_f32_64<<<dim3(Cn / 64, (Bn * Tn) / 64), blk, 0, stream>>>(
      attn_out, W_proj, out, Bn * Tn, Cn, Cn);
}

// Round 5
// 281.335 us; speedup vs baseline: 23.3927x; 2.3534x over previous
//
#include <hip/hip_runtime.h>
#include <cstddef>
#include <cstdint>

#define Bn 4
#define Tn 2048
#define Cn 768
#define Hn 12

typedef __attribute__((ext_vector_type(8))) short short8v;
typedef __attribute__((ext_vector_type(4))) float f32x4;
typedef unsigned short ushort_t;

struct us4 { unsigned short x, y, z, w; };

__device__ inline unsigned short f2bf(float f) {
  union { float f; unsigned u; } v; v.f = f;
  unsigned r = v.u + 0x7FFFu + ((v.u >> 16) & 1u);
  return (unsigned short)(r >> 16);
}
__device__ inline float bf2f(unsigned short u) {
  union { unsigned u; float f; } v; v.u = ((unsigned)u) << 16;
  return v.f;
}

#define GLOAD_LDS16(gp, lp)                                                        \
  __builtin_amdgcn_global_load_lds(                                                \
      (const __attribute__((address_space(1))) void*)(gp),                         \
      (__attribute__((address_space(3))) void*)(lp), 16, 0, 0)

// ---------------- x -> hi/lo bf16 split ----------------
__global__ __launch_bounds__(256) void conv_x_split(const float* __restrict__ in,
                                                    ushort_t* __restrict__ hi,
                                                    ushort_t* __restrict__ lo, int n4) {
  int i = blockIdx.x * 256 + threadIdx.x;
  if (i >= n4) return;
  float4 v = reinterpret_cast<const float4*>(in)[i];
  us4 h, l;
  h.x = f2bf(v.x); l.x = f2bf(v.x - bf2f(h.x));
  h.y = f2bf(v.y); l.y = f2bf(v.y - bf2f(h.y));
  h.z = f2bf(v.z); l.z = f2bf(v.z - bf2f(h.z));
  h.w = f2bf(v.w); l.w = f2bf(v.w - bf2f(h.w));
  reinterpret_cast<us4*>(hi)[i] = h;
  reinterpret_cast<us4*>(lo)[i] = l;
}

// ---------------- W[rows][cols] -> WT[cols][rows] bf16 (optionally hi+lo) --------
template <int SPLIT>
__global__ __launch_bounds__(256) void conv_wT(const float* __restrict__ W,
                                               ushort_t* __restrict__ WTh,
                                               ushort_t* __restrict__ WTl,
                                               int rows, int cols) {
  __shared__ float t[64][65];
  const int r0 = blockIdx.y * 64, c0 = blockIdx.x * 64;
  const int tid = threadIdx.x;
  const int c4 = (tid & 15) << 2;
  #pragma unroll
  for (int rr = 0; rr < 4; ++rr) {
    int r = rr * 16 + (tid >> 4);
    float4 v = *reinterpret_cast<const float4*>(&W[(size_t)(r0 + r) * cols + c0 + c4]);
    t[r][c4] = v.x; t[r][c4 + 1] = v.y; t[r][c4 + 2] = v.z; t[r][c4 + 3] = v.w;
  }
  __syncthreads();
  const int r4 = (tid & 15) << 2;
  #pragma unroll
  for (int cc = 0; cc < 4; ++cc) {
    int c = cc * 16 + (tid >> 4);
    float v0 = t[r4][c], v1 = t[r4 + 1][c], v2 = t[r4 + 2][c], v3 = t[r4 + 3][c];
    us4 h;
    h.x = f2bf(v0); h.y = f2bf(v1); h.z = f2bf(v2); h.w = f2bf(v3);
    *reinterpret_cast<us4*>(&WTh[(size_t)(c0 + c) * rows + r0 + r4]) = h;
    if (SPLIT) {
      us4 l;
      l.x = f2bf(v0 - bf2f(h.x)); l.y = f2bf(v1 - bf2f(h.y));
      l.z = f2bf(v2 - bf2f(h.z)); l.w = f2bf(v3 - bf2f(h.w));
      *reinterpret_cast<us4*>(&WTl[(size_t)(c0 + c) * rows + r0 + r4]) = l;
    }
  }
}

// ---------------- bf16 MFMA GEMM: C = A[M][K] @ Bt[N][K]^T, 128x128, BK=64 -------
// COMP=1: split-bf16 compensated (A = Ah+Al, B = Bh+Bl; 3-term MFMA, fp32 quality).
// MODE 0: C fp32.  MODE 1: fused qkv epilogue (q,k -> hi/lo pairs; v transposed).
template <int COMP, int MODE>
__global__ __launch_bounds__(256) void gemm_bf16(
    const ushort_t* __restrict__ Ah, const ushort_t* __restrict__ Al,
    const ushort_t* __restrict__ Bh, const ushort_t* __restrict__ Bl,
    int M, int N, int K, float* __restrict__ C,
    const float* __restrict__ lambda,
    ushort_t* __restrict__ qhp, ushort_t* __restrict__ qlp,
    ushort_t* __restrict__ khp, ushort_t* __restrict__ klp,
    ushort_t* __restrict__ vtp) {
  __shared__ ushort_t As[COMP + 1][128 * 64];
  __shared__ ushort_t Bs[COMP + 1][128 * 64];

  const int tid = threadIdx.x;
  const int w = tid >> 6;
  const int lane = tid & 63;
  const int lcol = lane & 15;
  const int g = lane >> 4;
  const int bm = blockIdx.y * 128;
  const int bn = blockIdx.x * 128;
  const int wr = (w >> 1) * 64;
  const int wc = (w & 1) * 64;
  const int srow = tid >> 3;
  const int sslot = tid & 7;

  f32x4 acc[4][4];
  #pragma unroll
  for (int m = 0; m < 4; ++m)
    #pragma unroll
    for (int n = 0; n < 4; ++n)
      acc[m][n] = (f32x4){0.f, 0.f, 0.f, 0.f};

  for (int k0 = 0; k0 < K; k0 += 64) {
    __syncthreads();
    #pragma unroll
    for (int i = 0; i < 4; ++i) {
      const int row = i * 32 + srow;
      const int kslot = sslot ^ (row & 7);
      const size_t ga = (size_t)(bm + row) * K + k0 + kslot * 8;
      const size_t gb = (size_t)(bn + row) * K + k0 + kslot * 8;
      const size_t ldst = (size_t)(i * 256 + tid) * 16;
      GLOAD_LDS16(Ah + ga, (char*)As[0] + ldst);
      GLOAD_LDS16(Bh + gb, (char*)Bs[0] + ldst);
      if (COMP) {
        GLOAD_LDS16(Al + ga, (char*)As[COMP] + ldst);
        GLOAD_LDS16(Bl + gb, (char*)Bs[COMP] + ldst);
      }
    }
    __syncthreads();
    #pragma unroll
    for (int kk = 0; kk < 2; ++kk) {
      short8v a0[4], b0[4], a1[4], b1[4];
      #pragma unroll
      for (int m = 0; m < 4; ++m) {
        int row = wr + m * 16 + lcol;
        int off = row * 128 + (((kk * 4 + g) ^ (row & 7)) << 4);
        a0[m] = *reinterpret_cast<const short8v*>((const char*)As[0] + off);
        if (COMP) a1[m] = *reinterpret_cast<const short8v*>((const char*)As[COMP] + off);
      }
      #pragma unroll
      for (int n = 0; n < 4; ++n) {
        int row = wc + n * 16 + lcol;
        int off = row * 128 + (((kk * 4 + g) ^ (row & 7)) << 4);
        b0[n] = *reinterpret_cast<const short8v*>((const char*)Bs[0] + off);
        if (COMP) b1[n] = *reinterpret_cast<const short8v*>((const char*)Bs[COMP] + off);
      }
      #pragma unroll
      for (int m = 0; m < 4; ++m)
        #pragma unroll
        for (int n = 0; n < 4; ++n) {
          acc[m][n] = __builtin_amdgcn_mfma_f32_16x16x32_bf16(a0[m], b0[n], acc[m][n], 0, 0, 0);
          if (COMP) {
            acc[m][n] = __builtin_amdgcn_mfma_f32_16x16x32_bf16(a0[m], b1[n], acc[m][n], 0, 0, 0);
            acc[m][n] = __builtin_amdgcn_mfma_f32_16x16x32_bf16(a1[m], b0[n], acc[m][n], 0, 0, 0);
          }
        }
    }
  }

  if (MODE == 0) {
    #pragma unroll
    for (int m = 0; m < 4; ++m) {
      const int rowm = bm + wr + m * 16 + g * 4;
      #pragma unroll
      for (int n = 0; n < 4; ++n) {
        const int col = bn + wc + n * 16 + lcol;
        #pragma unroll
        for (int j = 0; j < 4; ++j)
          C[(size_t)(rowm + j) * N + col] = acc[m][n][j];
      }
    }
  } else {
    const int seg = bn / Cn;                  // uniform (768 % 128 == 0)
    const int nloc_base = bn - seg * Cn + wc;
    #pragma unroll
    for (int m = 0; m < 4; ++m) {
      const int mg = bm + wr + m * 16 + g * 4;
      const int bidx = mg >> 11;
      const int tbase = mg & (Tn - 1);
      float lgt[4];
      if (seg == 0) {
        #pragma unroll
        for (int j = 0; j < 4; ++j) lgt[j] = logf((float)(tbase + j) + 1.0f);
      }
      #pragma unroll
      for (int n = 0; n < 4; ++n) {
        const int nloc = nloc_base + n * 16 + lcol;
        const int h = nloc >> 6;
        const int d = nloc & 63;
        const size_t bhh = (size_t)(bidx * Hn + h);
        if (seg == 0) {
          const float lam = lambda[h];
          #pragma unroll
          for (int j = 0; j < 4; ++j) {
            float val = acc[m][n][j] * (0.125f * (1.0f + lam * lgt[j]));
            unsigned short hi = f2bf(val);
            unsigned short lo = f2bf(val - bf2f(hi));
            size_t idx = (bhh * Tn + tbase + j) * 64 + d;
            qhp[idx] = hi; qlp[idx] = lo;
          }
        } else if (seg == 1) {
          #pragma unroll
          for (int j = 0; j < 4; ++j) {
            float val = acc[m][n][j];
            unsigned short hi = f2bf(val);
            unsigned short lo = f2bf(val - bf2f(hi));
            size_t idx = (bhh * Tn + tbase + j) * 64 + d;
            khp[idx] = hi; klp[idx] = lo;
          }
        } else {
          #pragma unroll
          for (int j = 0; j < 4; ++j)
            vtp[(bhh * 64 + d) * Tn + tbase + j] = f2bf(acc[m][n][j]);
        }
      }
    }
  }
}

// ---------------- MFMA flash-style relu-attention (compensated QK^T) -------------
__global__ __launch_bounds__(256) void attn_mfma(
    const ushort_t* __restrict__ qh, const ushort_t* __restrict__ ql,
    const ushort_t* __restrict__ kh, const ushort_t* __restrict__ kl,
    const ushort_t* __restrict__ vt, const float* __restrict__ attn_mask,
    ushort_t* __restrict__ ao) {
  const int qt = blockIdx.x & 31;
  const int bh = blockIdx.x >> 5;
  const int b = bh / Hn, h = bh % Hn;
  const int tid = threadIdx.x;
  const int w = tid >> 6;
  const int lane = tid & 63;
  const int lcol = lane & 15;
  const int g = lane >> 4;

  __shared__ ushort_t Kh_lds[64][72];
  __shared__ ushort_t Kl_lds[64][72];
  __shared__ ushort_t V_lds[64][72];
  __shared__ ushort_t P_lds[4][16][72];
  __shared__ float mk[64];

  const size_t qoff = ((size_t)bh * Tn + qt * 64 + w * 16 + lcol) * 64;
  short8v qf0h = *reinterpret_cast<const short8v*>(qh + qoff + g * 8);
  short8v qf1h = *reinterpret_cast<const short8v*>(qh + qoff + 32 + g * 8);
  short8v qf0l = *reinterpret_cast<const short8v*>(ql + qoff + g * 8);
  short8v qf1l = *reinterpret_cast<const short8v*>(ql + qoff + 32 + g * 8);

  f32x4 o[4];
  #pragma unroll
  for (int dt = 0; dt < 4; ++dt) o[dt] = (f32x4){0.f, 0.f, 0.f, 0.f};
  float dsum[4] = {0.f, 0.f, 0.f, 0.f};

  for (int kt = 0; kt <= qt; ++kt) {
    __syncthreads();
    {
      const ushort_t* khs = kh + ((size_t)bh * Tn + kt * 64) * 64;
      const ushort_t* kls = kl + ((size_t)bh * Tn + kt * 64) * 64;
      const ushort_t* vs  = vt + (size_t)bh * 64 * Tn + kt * 64;
      #pragma unroll
      for (int it = 0; it < 2; ++it) {
        int s_ = tid + it * 256;
        int r = s_ >> 3, c8 = (s_ & 7) * 8;
        *reinterpret_cast<short8v*>(&Kh_lds[r][c8]) =
            *reinterpret_cast<const short8v*>(khs + r * 64 + c8);
        *reinterpret_cast<short8v*>(&Kl_lds[r][c8]) =
            *reinterpret_cast<const short8v*>(kls + r * 64 + c8);
        *reinterpret_cast<short8v*>(&V_lds[r][c8]) =
            *reinterpret_cast<const short8v*>(vs + (size_t)r * Tn + c8);
      }
      if (tid < 64) mk[tid] = attn_mask[b * Tn + kt * 64 + tid];
    }
    __syncthreads();

    const bool diag = (kt == qt);
    #pragma unroll
    for (int c = 0; c < 4; ++c) {
      f32x4 s = (f32x4){0.f, 0.f, 0.f, 0.f};
      short8v kf0h = *reinterpret_cast<const short8v*>(&Kh_lds[c * 16 + lcol][g * 8]);
      short8v kf1h = *reinterpret_cast<const short8v*>(&Kh_lds[c * 16 + lcol][32 + g * 8]);
      short8v kf0l = *reinterpret_cast<const short8v*>(&Kl_lds[c * 16 + lcol][g * 8]);
      short8v kf1l = *reinterpret_cast<const short8v*>(&Kl_lds[c * 16 + lcol][32 + g * 8]);
      s = __builtin_amdgcn_mfma_f32_16x16x32_bf16(qf0h, kf0h, s, 0, 0, 0);
      s = __builtin_amdgcn_mfma_f32_16x16x32_bf16(qf1h, kf1h, s, 0, 0, 0);
      s = __builtin_amdgcn_mfma_f32_16x16x32_bf16(qf0h, kf0l, s, 0, 0, 0);
      s = __builtin_amdgcn_mfma_f32_16x16x32_bf16(qf1h, kf1l, s, 0, 0, 0);
      s = __builtin_amdgcn_mfma_f32_16x16x32_bf16(qf0l, kf0h, s, 0, 0, 0);
      s = __builtin_amdgcn_mfma_f32_16x16x32_bf16(qf1l, kf1h, s, 0, 0, 0);
      const float m = mk[c * 16 + lcol];
      #pragma unroll
      for (int r = 0; r < 4; ++r) {
        float sv = fmaxf(s[r], 0.f) * m;
        if (diag) {
          int qr = w * 16 + g * 4 + r;
          int kr = c * 16 + lcol;
          if (kr > qr) sv = 0.f;
        }
        unsigned short pr = f2bf(sv);
        dsum[r] += bf2f(pr);
        P_lds[w][g * 4 + r][c * 16 + lcol] = pr;
      }
    }
    __syncthreads();

    short8v pf0 = *reinterpret_cast<const short8v*>(&P_lds[w][lcol][g * 8]);
    short8v pf1 = *reinterpret_cast<const short8v*>(&P_lds[w][lcol][32 + g * 8]);
    #pragma unroll
    for (int dt = 0; dt < 4; ++dt) {
      short8v vf0 = *reinterpret_cast<const short8v*>(&V_lds[dt * 16 + lcol][g * 8]);
      short8v vf1 = *reinterpret_cast<const short8v*>(&V_lds[dt * 16 + lcol][32 + g * 8]);
      o[dt] = __builtin_amdgcn_mfma_f32_16x16x32_bf16(pf0, vf0, o[dt], 0, 0, 0);
      o[dt] = __builtin_amdgcn_mfma_f32_16x16x32_bf16(pf1, vf1, o[dt], 0, 0, 0);
    }
  }

  #pragma unroll
  for (int r = 0; r < 4; ++r) {
    float d = dsum[r];
    d += __shfl_xor(d, 1); d += __shfl_xor(d, 2);
    d += __shfl_xor(d, 4); d += __shfl_xor(d, 8);
    dsum[r] = 1.0f / (d + 1e-9f);
  }
  ushort_t* ob = ao + ((size_t)b * Tn + qt * 64 + w * 16) * Cn + h * 64;
  #pragma unroll
  for (int dt = 0; dt < 4; ++dt)
    #pragma unroll
    for (int r = 0; r < 4; ++r)
      ob[(size_t)(g * 4 + r) * Cn + dt * 16 + lcol] = f2bf(o[dt][r] * dsum[r]);
}

extern "C" void kernel_launch(void* const* d_in, const int* in_sizes, int n_in,
                              void* d_out, int out_size, void* d_ws, size_t ws_size,
                              hipStream_t stream) {
  const float* x         = (const float*)d_in[0];
  const float* attn_mask = (const float*)d_in[1];
  const float* lambda    = (const float*)d_in[2];
  const float* W_attn    = (const float*)d_in[3];
  const float* W_proj    = (const float*)d_in[4];
  float* out = (float*)d_out;

  const size_t nBTC = (size_t)Bn * Tn * Cn;        // 6.29M
  const size_t nW1  = (size_t)Cn * 3 * Cn;         // 1.77M
  const size_t nW2  = (size_t)Cn * Cn;             // 0.59M
  ushort_t* xh  = (ushort_t*)d_ws;
  ushort_t* xl  = xh + nBTC;
  ushort_t* WhT = xl + nBTC;
  ushort_t* WlT = WhT + nW1;
  ushort_t* WpT = WlT + nW1;
  ushort_t* qh  = WpT + nW2;
  ushort_t* ql  = qh + nBTC;
  ushort_t* kh  = ql + nBTC;
  ushort_t* kl  = kh + nBTC;
  ushort_t* vt  = kl + nBTC;
  ushort_t* ao  = xh;   // xh dead after gemm1; reuse for attention output

  dim3 blk(256);

  conv_x_split<<<dim3((unsigned)(nBTC / 4 / 256)), blk, 0, stream>>>(
      x, xh, xl, (int)(nBTC / 4));
  conv_wT<1><<<dim3(36, 12), blk, 0, stream>>>(W_attn, WhT, WlT, Cn, 3 * Cn);
  conv_wT<0><<<dim3(12, 12), blk, 0, stream>>>(W_proj, WpT, nullptr, Cn, Cn);

  gemm_bf16<1, 1><<<dim3(18, 64), blk, 0, stream>>>(
      xh, xl, WhT, WlT, Bn * Tn, 3 * Cn, Cn, nullptr, lambda, qh, ql, kh, kl, vt);

  attn_mfma<<<dim3(Bn * Hn * (Tn / 64)), blk, 0, stream>>>(
      qh, ql, kh, kl, vt, attn_mask, ao);

  gemm_bf16<0, 0><<<dim3(6, 64), blk, 0, stream>>>(
      ao, nullptr, WpT, nullptr, Bn * Tn, Cn, Cn, out, nullptr,
      nullptr, nullptr, nullptr, nullptr, nullptr);
}

// Round 6
// 247.248 us; speedup vs baseline: 26.6177x; 1.1379x over previous
//
#include <hip/hip_runtime.h>
#include <cstddef>
#include <cstdint>

#define Bn 4
#define Tn 2048
#define Cn 768
#define Hn 12

typedef __attribute__((ext_vector_type(8))) short short8v;
typedef __attribute__((ext_vector_type(4))) float f32x4;
typedef unsigned short ushort_t;

struct us4 { unsigned short x, y, z, w; };

__device__ inline unsigned short f2bf(float f) {
  union { float f; unsigned u; } v; v.f = f;
  unsigned r = v.u + 0x7FFFu + ((v.u >> 16) & 1u);
  return (unsigned short)(r >> 16);
}
__device__ inline float bf2f(unsigned short u) {
  union { unsigned u; float f; } v; v.u = ((unsigned)u) << 16;
  return v.f;
}
__device__ inline unsigned cvt_pk_bf16(float lo, float hi) {
  unsigned r;
  asm("v_cvt_pk_bf16_f32 %0, %1, %2" : "=v"(r) : "v"(lo), "v"(hi));
  return r;
}
__device__ inline float u2f(unsigned u) {
  union { unsigned u; float f; } v; v.u = u; return v.f;
}

#define GLOAD_LDS16(gp, lp)                                                        \
  __builtin_amdgcn_global_load_lds(                                                \
      (const __attribute__((address_space(1))) void*)(gp),                         \
      (__attribute__((address_space(3))) void*)(lp), 16, 0, 0)

// ---------------- x -> hi/lo bf16 split ----------------
__global__ __launch_bounds__(256) void conv_x_split(const float* __restrict__ in,
                                                    ushort_t* __restrict__ hi,
                                                    ushort_t* __restrict__ lo, int n4) {
  int i = blockIdx.x * 256 + threadIdx.x;
  if (i >= n4) return;
  float4 v = reinterpret_cast<const float4*>(in)[i];
  us4 h, l;
  h.x = f2bf(v.x); l.x = f2bf(v.x - bf2f(h.x));
  h.y = f2bf(v.y); l.y = f2bf(v.y - bf2f(h.y));
  h.z = f2bf(v.z); l.z = f2bf(v.z - bf2f(h.z));
  h.w = f2bf(v.w); l.w = f2bf(v.w - bf2f(h.w));
  reinterpret_cast<us4*>(hi)[i] = h;
  reinterpret_cast<us4*>(lo)[i] = l;
}

// ---------------- W[rows][cols] -> WT[cols][rows] bf16 (optionally hi+lo) --------
template <int SPLIT>
__global__ __launch_bounds__(256) void conv_wT(const float* __restrict__ W,
                                               ushort_t* __restrict__ WTh,
                                               ushort_t* __restrict__ WTl,
                                               int rows, int cols) {
  __shared__ float t[64][65];
  const int r0 = blockIdx.y * 64, c0 = blockIdx.x * 64;
  const int tid = threadIdx.x;
  const int c4 = (tid & 15) << 2;
  #pragma unroll
  for (int rr = 0; rr < 4; ++rr) {
    int r = rr * 16 + (tid >> 4);
    float4 v = *reinterpret_cast<const float4*>(&W[(size_t)(r0 + r) * cols + c0 + c4]);
    t[r][c4] = v.x; t[r][c4 + 1] = v.y; t[r][c4 + 2] = v.z; t[r][c4 + 3] = v.w;
  }
  __syncthreads();
  const int r4 = (tid & 15) << 2;
  #pragma unroll
  for (int cc = 0; cc < 4; ++cc) {
    int c = cc * 16 + (tid >> 4);
    float v0 = t[r4][c], v1 = t[r4 + 1][c], v2 = t[r4 + 2][c], v3 = t[r4 + 3][c];
    us4 h;
    h.x = f2bf(v0); h.y = f2bf(v1); h.z = f2bf(v2); h.w = f2bf(v3);
    *reinterpret_cast<us4*>(&WTh[(size_t)(c0 + c) * rows + r0 + r4]) = h;
    if (SPLIT) {
      us4 l;
      l.x = f2bf(v0 - bf2f(h.x)); l.y = f2bf(v1 - bf2f(h.y));
      l.z = f2bf(v2 - bf2f(h.z)); l.w = f2bf(v3 - bf2f(h.w));
      *reinterpret_cast<us4*>(&WTl[(size_t)(c0 + c) * rows + r0 + r4]) = l;
    }
  }
}

// ---------------- bf16 MFMA GEMM: C = A[M][K] @ Bt[N][K]^T, 128x128, BK=64 -------
// COMP=1: split-bf16 compensated (3-term MFMA, fp32 quality).
// MODE 0: C fp32.  MODE 1: fused qkv epilogue (q,k -> hi/lo pairs; v transposed).
template <int COMP, int MODE>
__global__ __launch_bounds__(256) void gemm_bf16(
    const ushort_t* __restrict__ Ah, const ushort_t* __restrict__ Al,
    const ushort_t* __restrict__ Bh, const ushort_t* __restrict__ Bl,
    int M, int N, int K, int bn_off, float* __restrict__ C,
    const float* __restrict__ lambda,
    ushort_t* __restrict__ qhp, ushort_t* __restrict__ qlp,
    ushort_t* __restrict__ khp, ushort_t* __restrict__ klp,
    ushort_t* __restrict__ vtp) {
  __shared__ ushort_t As[COMP + 1][128 * 64];
  __shared__ ushort_t Bs[COMP + 1][128 * 64];

  const int tid = threadIdx.x;
  const int w = tid >> 6;
  const int lane = tid & 63;
  const int lcol = lane & 15;
  const int g = lane >> 4;
  const int bm = blockIdx.y * 128;
  const int bn = blockIdx.x * 128 + bn_off;
  const int wr = (w >> 1) * 64;
  const int wc = (w & 1) * 64;
  const int srow = tid >> 3;
  const int sslot = tid & 7;

  f32x4 acc[4][4];
  #pragma unroll
  for (int m = 0; m < 4; ++m)
    #pragma unroll
    for (int n = 0; n < 4; ++n)
      acc[m][n] = (f32x4){0.f, 0.f, 0.f, 0.f};

  for (int k0 = 0; k0 < K; k0 += 64) {
    __syncthreads();
    #pragma unroll
    for (int i = 0; i < 4; ++i) {
      const int row = i * 32 + srow;
      const int kslot = sslot ^ (row & 7);
      const size_t ga = (size_t)(bm + row) * K + k0 + kslot * 8;
      const size_t gb = (size_t)(bn + row) * K + k0 + kslot * 8;
      const size_t ldst = (size_t)(i * 256 + tid) * 16;
      GLOAD_LDS16(Ah + ga, (char*)As[0] + ldst);
      GLOAD_LDS16(Bh + gb, (char*)Bs[0] + ldst);
      if (COMP) {
        GLOAD_LDS16(Al + ga, (char*)As[COMP] + ldst);
        GLOAD_LDS16(Bl + gb, (char*)Bs[COMP] + ldst);
      }
    }
    __syncthreads();
    #pragma unroll
    for (int kk = 0; kk < 2; ++kk) {
      short8v a0[4], b0[4], a1[4], b1[4];
      #pragma unroll
      for (int m = 0; m < 4; ++m) {
        int row = wr + m * 16 + lcol;
        int off = row * 128 + (((kk * 4 + g) ^ (row & 7)) << 4);
        a0[m] = *reinterpret_cast<const short8v*>((const char*)As[0] + off);
        if (COMP) a1[m] = *reinterpret_cast<const short8v*>((const char*)As[COMP] + off);
      }
      #pragma unroll
      for (int n = 0; n < 4; ++n) {
        int row = wc + n * 16 + lcol;
        int off = row * 128 + (((kk * 4 + g) ^ (row & 7)) << 4);
        b0[n] = *reinterpret_cast<const short8v*>((const char*)Bs[0] + off);
        if (COMP) b1[n] = *reinterpret_cast<const short8v*>((const char*)Bs[COMP] + off);
      }
      __builtin_amdgcn_s_setprio(1);
      #pragma unroll
      for (int m = 0; m < 4; ++m)
        #pragma unroll
        for (int n = 0; n < 4; ++n) {
          acc[m][n] = __builtin_amdgcn_mfma_f32_16x16x32_bf16(a0[m], b0[n], acc[m][n], 0, 0, 0);
          if (COMP) {
            acc[m][n] = __builtin_amdgcn_mfma_f32_16x16x32_bf16(a0[m], b1[n], acc[m][n], 0, 0, 0);
            acc[m][n] = __builtin_amdgcn_mfma_f32_16x16x32_bf16(a1[m], b0[n], acc[m][n], 0, 0, 0);
          }
        }
      __builtin_amdgcn_s_setprio(0);
    }
  }

  if (MODE == 0) {
    #pragma unroll
    for (int m = 0; m < 4; ++m) {
      const int rowm = bm + wr + m * 16 + g * 4;
      #pragma unroll
      for (int n = 0; n < 4; ++n) {
        const int col = bn + wc + n * 16 + lcol;
        #pragma unroll
        for (int j = 0; j < 4; ++j)
          C[(size_t)(rowm + j) * N + col] = acc[m][n][j];
      }
    }
  } else {
    const int seg = bn / Cn;                  // uniform (768 % 128 == 0)
    const int nloc_base = bn - seg * Cn + wc;
    #pragma unroll
    for (int m = 0; m < 4; ++m) {
      const int mg = bm + wr + m * 16 + g * 4;
      const int bidx = mg >> 11;
      const int tbase = mg & (Tn - 1);
      float lgt[4];
      if (seg == 0) {
        #pragma unroll
        for (int j = 0; j < 4; ++j) lgt[j] = logf((float)(tbase + j) + 1.0f);
      }
      #pragma unroll
      for (int n = 0; n < 4; ++n) {
        const int nloc = nloc_base + n * 16 + lcol;
        const int h = nloc >> 6;
        const int d = nloc & 63;
        const size_t bhh = (size_t)(bidx * Hn + h);
        if (seg == 0) {
          const float lam = lambda[h];
          #pragma unroll
          for (int j = 0; j < 4; ++j) {
            float val = acc[m][n][j] * (0.125f * (1.0f + lam * lgt[j]));
            unsigned short hi = f2bf(val);
            unsigned short lo = f2bf(val - bf2f(hi));
            size_t idx = (bhh * Tn + tbase + j) * 64 + d;
            qhp[idx] = hi; qlp[idx] = lo;
          }
        } else if (seg == 1) {
          #pragma unroll
          for (int j = 0; j < 4; ++j) {
            float val = acc[m][n][j];
            unsigned short hi = f2bf(val);
            unsigned short lo = f2bf(val - bf2f(hi));
            size_t idx = (bhh * Tn + tbase + j) * 64 + d;
            khp[idx] = hi; klp[idx] = lo;
          }
        } else {
          #pragma unroll
          for (int j = 0; j < 4; ++j)
            vtp[(bhh * 64 + d) * Tn + tbase + j] = f2bf(acc[m][n][j]);
        }
      }
    }
  }
}

// ---------------- MFMA flash-style relu-attention, 128 q-rows/block -------------
// Balanced (bh,qt) mapping: CU-resident triples of qt sum to 22-23.
__global__ __launch_bounds__(256) void attn_mfma(
    const ushort_t* __restrict__ qh, const ushort_t* __restrict__ ql,
    const ushort_t* __restrict__ kh, const ushort_t* __restrict__ kl,
    const ushort_t* __restrict__ vt, const float* __restrict__ attn_mask,
    ushort_t* __restrict__ ao) {
  static const int QT1[16] = {15,13,11,9,7,5,3,1,14,12,10,8,6,4,2,0};
  static const int QT2[16] = {7,9,10,11,12,13,14,15,0,1,2,3,4,5,6,8};
  const int cc_ = blockIdx.x & 255;
  const int rr_ = blockIdx.x >> 8;           // 0..2
  const int bh  = (cc_ >> 4) + (rr_ << 4);   // 0..47
  const int ii_ = cc_ & 15;
  const int qt  = (rr_ == 0) ? ii_ : (rr_ == 1 ? QT1[ii_] : QT2[ii_]);
  const int b = bh / Hn, h = bh % Hn;
  const int tid = threadIdx.x;
  const int w = tid >> 6, lane = tid & 63, lcol = lane & 15, g = lane >> 4;

  __shared__ ushort_t Kh_lds[64 * 64];
  __shared__ ushort_t Kl_lds[64 * 64];
  __shared__ ushort_t V_lds[64 * 64];
  __shared__ ushort_t P_lds[4][2][16][72];
  __shared__ float mk[64];

  // Q fragments for the wave's two 16-row groups
  short8v qfh[2][2], qfl[2][2];
  #pragma unroll
  for (int m = 0; m < 2; ++m) {
    const size_t qoff = ((size_t)bh * Tn + qt * 128 + w * 32 + m * 16 + lcol) * 64;
    qfh[m][0] = *reinterpret_cast<const short8v*>(qh + qoff + g * 8);
    qfh[m][1] = *reinterpret_cast<const short8v*>(qh + qoff + 32 + g * 8);
    qfl[m][0] = *reinterpret_cast<const short8v*>(ql + qoff + g * 8);
    qfl[m][1] = *reinterpret_cast<const short8v*>(ql + qoff + 32 + g * 8);
  }

  f32x4 o[2][4];
  float dsum[2][4];
  #pragma unroll
  for (int m = 0; m < 2; ++m) {
    #pragma unroll
    for (int dt = 0; dt < 4; ++dt) o[m][dt] = (f32x4){0.f, 0.f, 0.f, 0.f};
    #pragma unroll
    for (int r = 0; r < 4; ++r) dsum[m][r] = 0.f;
  }

  const int ntiles = 2 * qt + 2;
  for (int kt = 0; kt < ntiles; ++kt) {
    __syncthreads();
    {
      const ushort_t* ks = kh + ((size_t)bh * Tn + kt * 64) * 64;
      const ushort_t* ls = kl + ((size_t)bh * Tn + kt * 64) * 64;
      const ushort_t* vs = vt + (size_t)bh * 64 * Tn + kt * 64;
      #pragma unroll
      for (int it = 0; it < 2; ++it) {
        const int s = it * 256 + tid;
        const int row = s >> 3, sslot = s & 7;
        const int swz = (sslot ^ (row & 7)) * 8;
        GLOAD_LDS16(ks + row * 64 + swz, (char*)Kh_lds + (size_t)s * 16);
        GLOAD_LDS16(ls + row * 64 + swz, (char*)Kl_lds + (size_t)s * 16);
        GLOAD_LDS16(vs + (size_t)row * Tn + swz, (char*)V_lds + (size_t)s * 16);
      }
      if (tid < 64) mk[tid] = attn_mask[b * Tn + kt * 64 + tid];
    }
    __syncthreads();

    bool active[2];
    #pragma unroll
    for (int m = 0; m < 2; ++m) {
      const int qg = qt * 128 + w * 32 + m * 16;   // global first q-row of group
      const bool skip = (kt * 64 > qg + 15);
      active[m] = !skip;
      if (skip) continue;
      const bool diag = (kt * 64 + 63 > qg);
      #pragma unroll
      for (int c = 0; c < 4; ++c) {
        const int row = c * 16 + lcol;
        const int roff = row * 128;
        const int s0 = (g ^ (row & 7)) << 4;
        const int s1 = ((4 + g) ^ (row & 7)) << 4;
        short8v kf0h = *reinterpret_cast<const short8v*>((const char*)Kh_lds + roff + s0);
        short8v kf1h = *reinterpret_cast<const short8v*>((const char*)Kh_lds + roff + s1);
        short8v kf0l = *reinterpret_cast<const short8v*>((const char*)Kl_lds + roff + s0);
        short8v kf1l = *reinterpret_cast<const short8v*>((const char*)Kl_lds + roff + s1);
        f32x4 s = (f32x4){0.f, 0.f, 0.f, 0.f};
        __builtin_amdgcn_s_setprio(1);
        s = __builtin_amdgcn_mfma_f32_16x16x32_bf16(qfh[m][0], kf0h, s, 0, 0, 0);
        s = __builtin_amdgcn_mfma_f32_16x16x32_bf16(qfh[m][1], kf1h, s, 0, 0, 0);
        s = __builtin_amdgcn_mfma_f32_16x16x32_bf16(qfh[m][0], kf0l, s, 0, 0, 0);
        s = __builtin_amdgcn_mfma_f32_16x16x32_bf16(qfh[m][1], kf1l, s, 0, 0, 0);
        s = __builtin_amdgcn_mfma_f32_16x16x32_bf16(qfl[m][0], kf0h, s, 0, 0, 0);
        s = __builtin_amdgcn_mfma_f32_16x16x32_bf16(qfl[m][1], kf1h, s, 0, 0, 0);
        __builtin_amdgcn_s_setprio(0);
        const float mval = mk[row];
        float sv[4];
        #pragma unroll
        for (int r = 0; r < 4; ++r) {
          float v = fmaxf(s[r], 0.f) * mval;
          if (diag) {
            const int kr = kt * 64 + row;
            const int qr = qg + g * 4 + r;
            v = (kr <= qr) ? v : 0.f;
          }
          sv[r] = v;
        }
        const unsigned p01 = cvt_pk_bf16(sv[0], sv[1]);
        const unsigned p23 = cvt_pk_bf16(sv[2], sv[3]);
        P_lds[w][m][g * 4 + 0][row] = (ushort_t)p01;
        P_lds[w][m][g * 4 + 1][row] = (ushort_t)(p01 >> 16);
        P_lds[w][m][g * 4 + 2][row] = (ushort_t)p23;
        P_lds[w][m][g * 4 + 3][row] = (ushort_t)(p23 >> 16);
        dsum[m][0] += u2f(p01 << 16);
        dsum[m][1] += u2f(p01 & 0xFFFF0000u);
        dsum[m][2] += u2f(p23 << 16);
        dsum[m][3] += u2f(p23 & 0xFFFF0000u);
      }
    }

    // PV — no barrier needed: P region is wave-private, V staged this tile.
    short8v pf[2][2];
    #pragma unroll
    for (int m = 0; m < 2; ++m)
      if (active[m]) {
        pf[m][0] = *reinterpret_cast<const short8v*>(&P_lds[w][m][lcol][g * 8]);
        pf[m][1] = *reinterpret_cast<const short8v*>(&P_lds[w][m][lcol][32 + g * 8]);
      }
    #pragma unroll
    for (int dt = 0; dt < 4; ++dt) {
      const int vrow = dt * 16 + lcol;
      const int vro = vrow * 128;
      short8v vf0 = *reinterpret_cast<const short8v*>(
          (const char*)V_lds + vro + ((g ^ (vrow & 7)) << 4));
      short8v vf1 = *reinterpret_cast<const short8v*>(
          (const char*)V_lds + vro + (((4 + g) ^ (vrow & 7)) << 4));
      __builtin_amdgcn_s_setprio(1);
      #pragma unroll
      for (int m = 0; m < 2; ++m)
        if (active[m]) {
          o[m][dt] = __builtin_amdgcn_mfma_f32_16x16x32_bf16(pf[m][0], vf0, o[m][dt], 0, 0, 0);
          o[m][dt] = __builtin_amdgcn_mfma_f32_16x16x32_bf16(pf[m][1], vf1, o[m][dt], 0, 0, 0);
        }
      __builtin_amdgcn_s_setprio(0);
    }
  }

  #pragma unroll
  for (int m = 0; m < 2; ++m) {
    float inv[4];
    #pragma unroll
    for (int r = 0; r < 4; ++r) {
      float d = dsum[m][r];
      d += __shfl_xor(d, 1); d += __shfl_xor(d, 2);
      d += __shfl_xor(d, 4); d += __shfl_xor(d, 8);
      inv[r] = 1.0f / (d + 1e-9f);
    }
    ushort_t* ob = ao + ((size_t)b * Tn + qt * 128 + w * 32 + m * 16) * Cn + h * 64;
    #pragma unroll
    for (int dt = 0; dt < 4; ++dt)
      #pragma unroll
      for (int r = 0; r < 4; ++r)
        ob[(size_t)(g * 4 + r) * Cn + dt * 16 + lcol] = f2bf(o[m][dt][r] * inv[r]);
  }
}

extern "C" void kernel_launch(void* const* d_in, const int* in_sizes, int n_in,
                              void* d_out, int out_size, void* d_ws, size_t ws_size,
                              hipStream_t stream) {
  const float* x         = (const float*)d_in[0];
  const float* attn_mask = (const float*)d_in[1];
  const float* lambda    = (const float*)d_in[2];
  const float* W_attn    = (const float*)d_in[3];
  const float* W_proj    = (const float*)d_in[4];
  float* out = (float*)d_out;

  const size_t nBTC = (size_t)Bn * Tn * Cn;        // 6.29M
  const size_t nW1  = (size_t)Cn * 3 * Cn;         // 1.77M
  const size_t nW2  = (size_t)Cn * Cn;             // 0.59M
  ushort_t* xh  = (ushort_t*)d_ws;
  ushort_t* xl  = xh + nBTC;
  ushort_t* WhT = xl + nBTC;
  ushort_t* WlT = WhT + nW1;
  ushort_t* WpT = WlT + nW1;
  ushort_t* qh  = WpT + nW2;
  ushort_t* ql  = qh + nBTC;
  ushort_t* kh  = ql + nBTC;
  ushort_t* kl  = kh + nBTC;
  ushort_t* vt  = kl + nBTC;
  ushort_t* ao  = xh;   // xh dead after gemm1; reuse for attention output

  dim3 blk(256);

  conv_x_split<<<dim3((unsigned)(nBTC / 4 / 256)), blk, 0, stream>>>(
      x, xh, xl, (int)(nBTC / 4));
  conv_wT<1><<<dim3(36, 12), blk, 0, stream>>>(W_attn, WhT, WlT, Cn, 3 * Cn);
  conv_wT<0><<<dim3(12, 12), blk, 0, stream>>>(W_proj, WpT, nullptr, Cn, Cn);

  // q,k columns: compensated GEMM
  gemm_bf16<1, 1><<<dim3(12, 64), blk, 0, stream>>>(
      xh, xl, WhT, WlT, Bn * Tn, 3 * Cn, Cn, 0, nullptr, lambda, qh, ql, kh, kl, vt);
  // v columns: plain bf16 GEMM
  gemm_bf16<0, 1><<<dim3(6, 64), blk, 0, stream>>>(
      xh, nullptr, WhT, nullptr, Bn * Tn, 3 * Cn, Cn, 1536, nullptr, lambda,
      qh, ql, kh, kl, vt);

  attn_mfma<<<dim3(768), blk, 0, stream>>>(
      qh, ql, kh, kl, vt, attn_mask, ao);

  gemm_bf16<0, 0><<<dim3(6, 64), blk, 0, stream>>>(
      ao, nullptr, WpT, nullptr, Bn * Tn, Cn, Cn, 0, out, nullptr,
      nullptr, nullptr, nullptr, nullptr, nullptr);
}

// Round 7
// 216.209 us; speedup vs baseline: 30.4390x; 1.1436x over previous
//
#include <hip/hip_runtime.h>
#include <cstddef>
#include <cstdint>

#define Bn 4
#define Tn 2048
#define Cn 768
#define Hn 12

typedef __attribute__((ext_vector_type(8))) short short8v;
typedef __attribute__((ext_vector_type(4))) float f32x4;
typedef unsigned short ushort_t;

struct us4 { unsigned short x, y, z, w; };

__device__ inline unsigned short f2bf(float f) {
  union { float f; unsigned u; } v; v.f = f;
  unsigned r = v.u + 0x7FFFu + ((v.u >> 16) & 1u);
  return (unsigned short)(r >> 16);
}
__device__ inline float bf2f(unsigned short u) {
  union { unsigned u; float f; } v; v.u = ((unsigned)u) << 16;
  return v.f;
}
__device__ inline unsigned cvt_pk_bf16(float lo, float hi) {
  unsigned r;
  asm("v_cvt_pk_bf16_f32 %0, %1, %2" : "=v"(r) : "v"(lo), "v"(hi));
  return r;
}
__device__ inline float u2f(unsigned u) {
  union { unsigned u; float f; } v; v.u = u; return v.f;
}

#define GLOAD_LDS16(gp, lp)                                                        \
  __builtin_amdgcn_global_load_lds(                                                \
      (const __attribute__((address_space(1))) void*)(gp),                         \
      (__attribute__((address_space(3))) void*)(lp), 16, 0, 0)

// ---------------- x -> hi/lo bf16 split ----------------
__global__ __launch_bounds__(256) void conv_x_split(const float* __restrict__ in,
                                                    ushort_t* __restrict__ hi,
                                                    ushort_t* __restrict__ lo, int n4) {
  int i = blockIdx.x * 256 + threadIdx.x;
  if (i >= n4) return;
  float4 v = reinterpret_cast<const float4*>(in)[i];
  us4 h, l;
  h.x = f2bf(v.x); l.x = f2bf(v.x - bf2f(h.x));
  h.y = f2bf(v.y); l.y = f2bf(v.y - bf2f(h.y));
  h.z = f2bf(v.z); l.z = f2bf(v.z - bf2f(h.z));
  h.w = f2bf(v.w); l.w = f2bf(v.w - bf2f(h.w));
  reinterpret_cast<us4*>(hi)[i] = h;
  reinterpret_cast<us4*>(lo)[i] = l;
}

// ---------------- W[rows][cols] -> WT[cols][rows] bf16 (optionally hi+lo) --------
template <int SPLIT>
__global__ __launch_bounds__(256) void conv_wT(const float* __restrict__ W,
                                               ushort_t* __restrict__ WTh,
                                               ushort_t* __restrict__ WTl,
                                               int rows, int cols) {
  __shared__ float t[64][65];
  const int r0 = blockIdx.y * 64, c0 = blockIdx.x * 64;
  const int tid = threadIdx.x;
  const int c4 = (tid & 15) << 2;
  #pragma unroll
  for (int rr = 0; rr < 4; ++rr) {
    int r = rr * 16 + (tid >> 4);
    float4 v = *reinterpret_cast<const float4*>(&W[(size_t)(r0 + r) * cols + c0 + c4]);
    t[r][c4] = v.x; t[r][c4 + 1] = v.y; t[r][c4 + 2] = v.z; t[r][c4 + 3] = v.w;
  }
  __syncthreads();
  const int r4 = (tid & 15) << 2;
  #pragma unroll
  for (int cc = 0; cc < 4; ++cc) {
    int c = cc * 16 + (tid >> 4);
    float v0 = t[r4][c], v1 = t[r4 + 1][c], v2 = t[r4 + 2][c], v3 = t[r4 + 3][c];
    us4 h;
    h.x = f2bf(v0); h.y = f2bf(v1); h.z = f2bf(v2); h.w = f2bf(v3);
    *reinterpret_cast<us4*>(&WTh[(size_t)(c0 + c) * rows + r0 + r4]) = h;
    if (SPLIT) {
      us4 l;
      l.x = f2bf(v0 - bf2f(h.x)); l.y = f2bf(v1 - bf2f(h.y));
      l.z = f2bf(v2 - bf2f(h.z)); l.w = f2bf(v3 - bf2f(h.w));
      *reinterpret_cast<us4*>(&WTl[(size_t)(c0 + c) * rows + r0 + r4]) = l;
    }
  }
}

// ---------------- bf16 MFMA GEMM: C = A[M][K] @ Bt[N][K]^T, 128x128, BK=64 -------
// COMP=1: split-bf16 compensated (3-term MFMA, fp32 quality).
// MODE 0: C fp32.  MODE 1: fused qkv epilogue (q,k -> hi/lo pairs; v transposed).
template <int COMP, int MODE>
__global__ __launch_bounds__(256) void gemm_bf16(
    const ushort_t* __restrict__ Ah, const ushort_t* __restrict__ Al,
    const ushort_t* __restrict__ Bh, const ushort_t* __restrict__ Bl,
    int M, int N, int K, int bn_off, float* __restrict__ C,
    const float* __restrict__ lambda,
    ushort_t* __restrict__ qhp, ushort_t* __restrict__ qlp,
    ushort_t* __restrict__ khp, ushort_t* __restrict__ klp,
    ushort_t* __restrict__ vtp) {
  __shared__ ushort_t As[COMP + 1][128 * 64];
  __shared__ ushort_t Bs[COMP + 1][128 * 64];

  const int tid = threadIdx.x;
  const int w = tid >> 6;
  const int lane = tid & 63;
  const int lcol = lane & 15;
  const int g = lane >> 4;
  const int bm = blockIdx.y * 128;
  const int bn = blockIdx.x * 128 + bn_off;
  const int wr = (w >> 1) * 64;
  const int wc = (w & 1) * 64;
  const int srow = tid >> 3;
  const int sslot = tid & 7;

  f32x4 acc[4][4];
  #pragma unroll
  for (int m = 0; m < 4; ++m)
    #pragma unroll
    for (int n = 0; n < 4; ++n)
      acc[m][n] = (f32x4){0.f, 0.f, 0.f, 0.f};

  for (int k0 = 0; k0 < K; k0 += 64) {
    __syncthreads();
    #pragma unroll
    for (int i = 0; i < 4; ++i) {
      const int row = i * 32 + srow;
      const int kslot = sslot ^ (row & 7);
      const size_t ga = (size_t)(bm + row) * K + k0 + kslot * 8;
      const size_t gb = (size_t)(bn + row) * K + k0 + kslot * 8;
      const size_t ldst = (size_t)(i * 256 + tid) * 16;
      GLOAD_LDS16(Ah + ga, (char*)As[0] + ldst);
      GLOAD_LDS16(Bh + gb, (char*)Bs[0] + ldst);
      if (COMP) {
        GLOAD_LDS16(Al + ga, (char*)As[COMP] + ldst);
        GLOAD_LDS16(Bl + gb, (char*)Bs[COMP] + ldst);
      }
    }
    __syncthreads();
    #pragma unroll
    for (int kk = 0; kk < 2; ++kk) {
      short8v a0[4], b0[4], a1[4], b1[4];
      #pragma unroll
      for (int m = 0; m < 4; ++m) {
        int row = wr + m * 16 + lcol;
        int off = row * 128 + (((kk * 4 + g) ^ (row & 7)) << 4);
        a0[m] = *reinterpret_cast<const short8v*>((const char*)As[0] + off);
        if (COMP) a1[m] = *reinterpret_cast<const short8v*>((const char*)As[COMP] + off);
      }
      #pragma unroll
      for (int n = 0; n < 4; ++n) {
        int row = wc + n * 16 + lcol;
        int off = row * 128 + (((kk * 4 + g) ^ (row & 7)) << 4);
        b0[n] = *reinterpret_cast<const short8v*>((const char*)Bs[0] + off);
        if (COMP) b1[n] = *reinterpret_cast<const short8v*>((const char*)Bs[COMP] + off);
      }
      #pragma unroll
      for (int m = 0; m < 4; ++m)
        #pragma unroll
        for (int n = 0; n < 4; ++n) {
          acc[m][n] = __builtin_amdgcn_mfma_f32_16x16x32_bf16(a0[m], b0[n], acc[m][n], 0, 0, 0);
          if (COMP) {
            acc[m][n] = __builtin_amdgcn_mfma_f32_16x16x32_bf16(a0[m], b1[n], acc[m][n], 0, 0, 0);
            acc[m][n] = __builtin_amdgcn_mfma_f32_16x16x32_bf16(a1[m], b0[n], acc[m][n], 0, 0, 0);
          }
        }
    }
  }

  if (MODE == 0) {
    #pragma unroll
    for (int m = 0; m < 4; ++m) {
      const int rowm = bm + wr + m * 16 + g * 4;
      #pragma unroll
      for (int n = 0; n < 4; ++n) {
        const int col = bn + wc + n * 16 + lcol;
        #pragma unroll
        for (int j = 0; j < 4; ++j)
          C[(size_t)(rowm + j) * N + col] = acc[m][n][j];
      }
    }
  } else {
    const int seg = bn / Cn;                  // uniform (768 % 128 == 0)
    const int nloc_base = bn - seg * Cn + wc;
    #pragma unroll
    for (int m = 0; m < 4; ++m) {
      const int mg = bm + wr + m * 16 + g * 4;
      const int bidx = mg >> 11;
      const int tbase = mg & (Tn - 1);
      float lgt[4];
      if (seg == 0) {
        #pragma unroll
        for (int j = 0; j < 4; ++j) lgt[j] = logf((float)(tbase + j) + 1.0f);
      }
      #pragma unroll
      for (int n = 0; n < 4; ++n) {
        const int nloc = nloc_base + n * 16 + lcol;
        const int h = nloc >> 6;
        const int d = nloc & 63;
        const size_t bhh = (size_t)(bidx * Hn + h);
        if (seg == 0) {
          const float lam = lambda[h];
          #pragma unroll
          for (int j = 0; j < 4; ++j) {
            float val = acc[m][n][j] * (0.125f * (1.0f + lam * lgt[j]));
            unsigned short hi = f2bf(val);
            unsigned short lo = f2bf(val - bf2f(hi));
            size_t idx = (bhh * Tn + tbase + j) * 64 + d;
            qhp[idx] = hi; qlp[idx] = lo;
          }
        } else if (seg == 1) {
          #pragma unroll
          for (int j = 0; j < 4; ++j) {
            float val = acc[m][n][j];
            unsigned short hi = f2bf(val);
            unsigned short lo = f2bf(val - bf2f(hi));
            size_t idx = (bhh * Tn + tbase + j) * 64 + d;
            khp[idx] = hi; klp[idx] = lo;
          }
        } else {
          #pragma unroll
          for (int j = 0; j < 4; ++j)
            vtp[(bhh * 64 + d) * Tn + tbase + j] = f2bf(acc[m][n][j]);
        }
      }
    }
  }
}

// ---------------- MFMA flash-style relu-attention, 128 q-rows/block --------------
// 2-phase double-buffered K/V staging; q-side compensation everywhere; full
// (q+k)-side compensation only for qt==0 blocks (knife-edge rows t<128).
__global__ __launch_bounds__(256) void attn_mfma(
    const ushort_t* __restrict__ qh, const ushort_t* __restrict__ ql,
    const ushort_t* __restrict__ kh, const ushort_t* __restrict__ kl,
    const ushort_t* __restrict__ vt, const float* __restrict__ attn_mask,
    ushort_t* __restrict__ ao) {
  static const int QT1[16] = {15,13,11,9,7,5,3,1,14,12,10,8,6,4,2,0};
  static const int QT2[16] = {7,9,10,11,12,13,14,15,0,1,2,3,4,5,6,8};
  const int cc_ = blockIdx.x & 255;
  const int rr_ = blockIdx.x >> 8;           // 0..2
  const int bh  = (cc_ >> 4) + (rr_ << 4);   // 0..47
  const int ii_ = cc_ & 15;
  const int qt  = (rr_ == 0) ? ii_ : (rr_ == 1 ? QT1[ii_] : QT2[ii_]);
  const int b = bh / Hn, h = bh % Hn;
  const int tid = threadIdx.x;
  const int w = tid >> 6, lane = tid & 63, lcol = lane & 15, g = lane >> 4;

  __shared__ ushort_t Kh_lds[2][64 * 64];
  __shared__ ushort_t V_lds[2][64 * 64];
  __shared__ ushort_t P_lds[4][2][16][72];

  // Q fragments for the wave's two 16-row groups
  short8v qfh[2][2], qfl[2][2];
  #pragma unroll
  for (int m = 0; m < 2; ++m) {
    const size_t qoff = ((size_t)bh * Tn + qt * 128 + w * 32 + m * 16 + lcol) * 64;
    qfh[m][0] = *reinterpret_cast<const short8v*>(qh + qoff + g * 8);
    qfh[m][1] = *reinterpret_cast<const short8v*>(qh + qoff + 32 + g * 8);
    qfl[m][0] = *reinterpret_cast<const short8v*>(ql + qoff + g * 8);
    qfl[m][1] = *reinterpret_cast<const short8v*>(ql + qoff + 32 + g * 8);
  }

  f32x4 o[2][4];
  float dsum[2][4];
  #pragma unroll
  for (int m = 0; m < 2; ++m) {
    #pragma unroll
    for (int dt = 0; dt < 4; ++dt) o[m][dt] = (f32x4){0.f, 0.f, 0.f, 0.f};
    #pragma unroll
    for (int r = 0; r < 4; ++r) dsum[m][r] = 0.f;
  }

  float mv_cur[4], mv_nxt[4];

  auto STAGE = [&](int kt, int d) {
    const ushort_t* ks = kh + ((size_t)bh * Tn + kt * 64) * 64;
    const ushort_t* vs = vt + (size_t)bh * 64 * Tn + kt * 64;
    #pragma unroll
    for (int it = 0; it < 2; ++it) {
      const int s = it * 256 + tid;
      const int row = s >> 3, sslot = s & 7;
      const int swz = (sslot ^ (row & 7)) * 8;
      GLOAD_LDS16(ks + row * 64 + swz, (char*)Kh_lds[d] + (size_t)s * 16);
      GLOAD_LDS16(vs + (size_t)row * Tn + swz, (char*)V_lds[d] + (size_t)s * 16);
    }
  };
  auto STAGE_KL = [&](int kt) {   // qt==0 only: Kl parked in Kh_lds[1]
    const ushort_t* ls = kl + ((size_t)bh * Tn + kt * 64) * 64;
    #pragma unroll
    for (int it = 0; it < 2; ++it) {
      const int s = it * 256 + tid;
      const int row = s >> 3, sslot = s & 7;
      const int swz = (sslot ^ (row & 7)) * 8;
      GLOAD_LDS16(ls + row * 64 + swz, (char*)Kh_lds[1] + (size_t)s * 16);
    }
  };
  auto MLOAD = [&](int kt, float* mv) {
    #pragma unroll
    for (int c = 0; c < 4; ++c)
      mv[c] = attn_mask[b * Tn + kt * 64 + c * 16 + lcol];
  };

  auto COMPUTE = [&](int kt, int d, bool compk) {
    bool active[2];
    #pragma unroll
    for (int m = 0; m < 2; ++m) {
      const int qg = qt * 128 + w * 32 + m * 16;
      const bool skip = (kt * 64 > qg + 15);
      active[m] = !skip;
      if (skip) continue;
      const bool diag = (kt * 64 + 63 > qg);
      #pragma unroll
      for (int c = 0; c < 4; ++c) {
        const int row = c * 16 + lcol;
        const int roff = row * 128;
        const int s0 = (g ^ (row & 7)) << 4;
        const int s1 = ((4 + g) ^ (row & 7)) << 4;
        short8v kf0h = *reinterpret_cast<const short8v*>((const char*)Kh_lds[d] + roff + s0);
        short8v kf1h = *reinterpret_cast<const short8v*>((const char*)Kh_lds[d] + roff + s1);
        f32x4 s = (f32x4){0.f, 0.f, 0.f, 0.f};
        __builtin_amdgcn_s_setprio(1);
        s = __builtin_amdgcn_mfma_f32_16x16x32_bf16(qfh[m][0], kf0h, s, 0, 0, 0);
        s = __builtin_amdgcn_mfma_f32_16x16x32_bf16(qfh[m][1], kf1h, s, 0, 0, 0);
        s = __builtin_amdgcn_mfma_f32_16x16x32_bf16(qfl[m][0], kf0h, s, 0, 0, 0);
        s = __builtin_amdgcn_mfma_f32_16x16x32_bf16(qfl[m][1], kf1h, s, 0, 0, 0);
        if (compk) {
          short8v kf0l = *reinterpret_cast<const short8v*>((const char*)Kh_lds[1] + roff + s0);
          short8v kf1l = *reinterpret_cast<const short8v*>((const char*)Kh_lds[1] + roff + s1);
          s = __builtin_amdgcn_mfma_f32_16x16x32_bf16(qfh[m][0], kf0l, s, 0, 0, 0);
          s = __builtin_amdgcn_mfma_f32_16x16x32_bf16(qfh[m][1], kf1l, s, 0, 0, 0);
        }
        __builtin_amdgcn_s_setprio(0);
        const float mval = mv_cur[c];
        float sv[4];
        #pragma unroll
        for (int r = 0; r < 4; ++r) {
          float v = fmaxf(s[r], 0.f) * mval;
          if (diag) {
            const int kr = kt * 64 + row;
            const int qr = qg + g * 4 + r;
            v = (kr <= qr) ? v : 0.f;
          }
          sv[r] = v;
        }
        const unsigned p01 = cvt_pk_bf16(sv[0], sv[1]);
        const unsigned p23 = cvt_pk_bf16(sv[2], sv[3]);
        P_lds[w][m][g * 4 + 0][row] = (ushort_t)p01;
        P_lds[w][m][g * 4 + 1][row] = (ushort_t)(p01 >> 16);
        P_lds[w][m][g * 4 + 2][row] = (ushort_t)p23;
        P_lds[w][m][g * 4 + 3][row] = (ushort_t)(p23 >> 16);
        dsum[m][0] += u2f(p01 << 16);
        dsum[m][1] += u2f(p01 & 0xFFFF0000u);
        dsum[m][2] += u2f(p23 << 16);
        dsum[m][3] += u2f(p23 & 0xFFFF0000u);
      }
    }

    // PV — no extra barrier: P region is wave-private, V staged this tile.
    short8v pf[2][2];
    #pragma unroll
    for (int m = 0; m < 2; ++m)
      if (active[m]) {
        pf[m][0] = *reinterpret_cast<const short8v*>(&P_lds[w][m][lcol][g * 8]);
        pf[m][1] = *reinterpret_cast<const short8v*>(&P_lds[w][m][lcol][32 + g * 8]);
      }
    #pragma unroll
    for (int dt = 0; dt < 4; ++dt) {
      const int vrow = dt * 16 + lcol;
      const int vro = vrow * 128;
      short8v vf0 = *reinterpret_cast<const short8v*>(
          (const char*)V_lds[d] + vro + ((g ^ (vrow & 7)) << 4));
      short8v vf1 = *reinterpret_cast<const short8v*>(
          (const char*)V_lds[d] + vro + (((4 + g) ^ (vrow & 7)) << 4));
      __builtin_amdgcn_s_setprio(1);
      #pragma unroll
      for (int m = 0; m < 2; ++m)
        if (active[m]) {
          o[m][dt] = __builtin_amdgcn_mfma_f32_16x16x32_bf16(pf[m][0], vf0, o[m][dt], 0, 0, 0);
          o[m][dt] = __builtin_amdgcn_mfma_f32_16x16x32_bf16(pf[m][1], vf1, o[m][dt], 0, 0, 0);
        }
      __builtin_amdgcn_s_setprio(0);
    }
  };

  if (qt == 0) {
    // 2 tiles, sequential, full q+k compensation (knife-edge rows t<128)
    for (int kt = 0; kt < 2; ++kt) {
      STAGE(kt, 0);
      STAGE_KL(kt);
      MLOAD(kt, mv_cur);
      __syncthreads();
      COMPUTE(kt, 0, true);
      __syncthreads();
    }
  } else {
    const int ntiles = 2 * qt + 2;
    MLOAD(0, mv_cur);
    STAGE(0, 0);
    __syncthreads();
    for (int kt = 0; kt < ntiles; ++kt) {
      const int d = kt & 1;
      if (kt + 1 < ntiles) { STAGE(kt + 1, d ^ 1); MLOAD(kt + 1, mv_nxt); }
      COMPUTE(kt, d, false);
      __syncthreads();
      #pragma unroll
      for (int c = 0; c < 4; ++c) mv_cur[c] = mv_nxt[c];
    }
  }

  #pragma unroll
  for (int m = 0; m < 2; ++m) {
    float inv[4];
    #pragma unroll
    for (int r = 0; r < 4; ++r) {
      float d = dsum[m][r];
      d += __shfl_xor(d, 1); d += __shfl_xor(d, 2);
      d += __shfl_xor(d, 4); d += __shfl_xor(d, 8);
      inv[r] = 1.0f / (d + 1e-9f);
    }
    ushort_t* ob = ao + ((size_t)b * Tn + qt * 128 + w * 32 + m * 16) * Cn + h * 64;
    #pragma unroll
    for (int dt = 0; dt < 4; ++dt)
      #pragma unroll
      for (int r = 0; r < 4; ++r)
        ob[(size_t)(g * 4 + r) * Cn + dt * 16 + lcol] = f2bf(o[m][dt][r] * inv[r]);
  }
}

extern "C" void kernel_launch(void* const* d_in, const int* in_sizes, int n_in,
                              void* d_out, int out_size, void* d_ws, size_t ws_size,
                              hipStream_t stream) {
  const float* x         = (const float*)d_in[0];
  const float* attn_mask = (const float*)d_in[1];
  const float* lambda    = (const float*)d_in[2];
  const float* W_attn    = (const float*)d_in[3];
  const float* W_proj    = (const float*)d_in[4];
  float* out = (float*)d_out;

  const size_t nBTC = (size_t)Bn * Tn * Cn;        // 6.29M
  const size_t nW1  = (size_t)Cn * 3 * Cn;         // 1.77M
  const size_t nW2  = (size_t)Cn * Cn;             // 0.59M
  ushort_t* xh  = (ushort_t*)d_ws;
  ushort_t* xl  = xh + nBTC;
  ushort_t* WhT = xl + nBTC;
  ushort_t* WlT = WhT + nW1;
  ushort_t* WpT = WlT + nW1;
  ushort_t* qh  = WpT + nW2;
  ushort_t* ql  = qh + nBTC;
  ushort_t* kh  = ql + nBTC;
  ushort_t* kl  = kh + nBTC;
  ushort_t* vt  = kl + nBTC;
  ushort_t* ao  = xh;   // xh dead after gemm1; reuse for attention output

  dim3 blk(256);

  conv_x_split<<<dim3((unsigned)(nBTC / 4 / 256)), blk, 0, stream>>>(
      x, xh, xl, (int)(nBTC / 4));
  conv_wT<1><<<dim3(36, 12), blk, 0, stream>>>(W_attn, WhT, WlT, Cn, 3 * Cn);
  conv_wT<0><<<dim3(12, 12), blk, 0, stream>>>(W_proj, WpT, nullptr, Cn, Cn);

  // q,k columns: compensated GEMM
  gemm_bf16<1, 1><<<dim3(12, 64), blk, 0, stream>>>(
      xh, xl, WhT, WlT, Bn * Tn, 3 * Cn, Cn, 0, nullptr, lambda, qh, ql, kh, kl, vt);
  // v columns: plain bf16 GEMM
  gemm_bf16<0, 1><<<dim3(6, 64), blk, 0, stream>>>(
      xh, nullptr, WhT, nullptr, Bn * Tn, 3 * Cn, Cn, 1536, nullptr, lambda,
      qh, ql, kh, kl, vt);

  attn_mfma<<<dim3(768), blk, 0, stream>>>(
      qh, ql, kh, kl, vt, attn_mask, ao);

  gemm_bf16<0, 0><<<dim3(6, 64), blk, 0, stream>>>(
      ao, nullptr, WpT, nullptr, Bn * Tn, Cn, Cn, 0, out, nullptr,
      nullptr, nullptr, nullptr, nullptr, nullptr);
}

// Round 8
// 201.108 us; speedup vs baseline: 32.7245x; 1.0751x over previous
//
#include <hip/hip_runtime.h>
#include <cstddef>
#include <cstdint>

#define Bn 4
#define Tn 2048
#define Cn 768
#define Hn 12

typedef __attribute__((ext_vector_type(8))) short short8v;
typedef __attribute__((ext_vector_type(4))) float f32x4;
typedef unsigned short ushort_t;

struct us4 { unsigned short x, y, z, w; };

__device__ inline unsigned short f2bf(float f) {
  union { float f; unsigned u; } v; v.f = f;
  unsigned r = v.u + 0x7FFFu + ((v.u >> 16) & 1u);
  return (unsigned short)(r >> 16);
}
__device__ inline float bf2f(unsigned short u) {
  union { unsigned u; float f; } v; v.u = ((unsigned)u) << 16;
  return v.f;
}
__device__ inline unsigned cvt_pk_bf16(float lo, float hi) {
  unsigned r;
  asm("v_cvt_pk_bf16_f32 %0, %1, %2" : "=v"(r) : "v"(lo), "v"(hi));
  return r;
}
__device__ inline float u2f(unsigned u) {
  union { unsigned u; float f; } v; v.u = u; return v.f;
}

#define GLOAD_LDS16(gp, lp)                                                        \
  __builtin_amdgcn_global_load_lds(                                                \
      (const __attribute__((address_space(1))) void*)(gp),                         \
      (__attribute__((address_space(3))) void*)(lp), 16, 0, 0)

// ---------------- x -> hi/lo bf16 split ----------------
__global__ __launch_bounds__(256) void conv_x_split(const float* __restrict__ in,
                                                    ushort_t* __restrict__ hi,
                                                    ushort_t* __restrict__ lo, int n4) {
  int i = blockIdx.x * 256 + threadIdx.x;
  if (i >= n4) return;
  float4 v = reinterpret_cast<const float4*>(in)[i];
  us4 h, l;
  h.x = f2bf(v.x); l.x = f2bf(v.x - bf2f(h.x));
  h.y = f2bf(v.y); l.y = f2bf(v.y - bf2f(h.y));
  h.z = f2bf(v.z); l.z = f2bf(v.z - bf2f(h.z));
  h.w = f2bf(v.w); l.w = f2bf(v.w - bf2f(h.w));
  reinterpret_cast<us4*>(hi)[i] = h;
  reinterpret_cast<us4*>(lo)[i] = l;
}

// ---------------- W[rows][cols] -> WT[cols][rows] bf16 (optionally hi+lo) --------
template <int SPLIT>
__global__ __launch_bounds__(256) void conv_wT(const float* __restrict__ W,
                                               ushort_t* __restrict__ WTh,
                                               ushort_t* __restrict__ WTl,
                                               int rows, int cols) {
  __shared__ float t[64][65];
  const int r0 = blockIdx.y * 64, c0 = blockIdx.x * 64;
  const int tid = threadIdx.x;
  const int c4 = (tid & 15) << 2;
  #pragma unroll
  for (int rr = 0; rr < 4; ++rr) {
    int r = rr * 16 + (tid >> 4);
    float4 v = *reinterpret_cast<const float4*>(&W[(size_t)(r0 + r) * cols + c0 + c4]);
    t[r][c4] = v.x; t[r][c4 + 1] = v.y; t[r][c4 + 2] = v.z; t[r][c4 + 3] = v.w;
  }
  __syncthreads();
  const int r4 = (tid & 15) << 2;
  #pragma unroll
  for (int cc = 0; cc < 4; ++cc) {
    int c = cc * 16 + (tid >> 4);
    float v0 = t[r4][c], v1 = t[r4 + 1][c], v2 = t[r4 + 2][c], v3 = t[r4 + 3][c];
    us4 h;
    h.x = f2bf(v0); h.y = f2bf(v1); h.z = f2bf(v2); h.w = f2bf(v3);
    *reinterpret_cast<us4*>(&WTh[(size_t)(c0 + c) * rows + r0 + r4]) = h;
    if (SPLIT) {
      us4 l;
      l.x = f2bf(v0 - bf2f(h.x)); l.y = f2bf(v1 - bf2f(h.y));
      l.z = f2bf(v2 - bf2f(h.z)); l.w = f2bf(v3 - bf2f(h.w));
      *reinterpret_cast<us4*>(&WTl[(size_t)(c0 + c) * rows + r0 + r4]) = l;
    }
  }
}

// ---------------- bf16 MFMA GEMM: C = A[M][K] @ Bt[N][K]^T, 128x128, BK=64 -------
// COMP=1: split-bf16 compensated (3-term MFMA, fp32 quality).
// MODE 0: C fp32.  MODE 1: fused qkv epilogue (q,k -> hi/lo pairs; v transposed).
// SLICE=1: bm = (y>>1)*Tn + (y&1)*128  (t<256 rows of each batch only).
template <int COMP, int MODE, int SLICE>
__global__ __launch_bounds__(256) void gemm_bf16(
    const ushort_t* __restrict__ Ah, const ushort_t* __restrict__ Al,
    const ushort_t* __restrict__ Bh, const ushort_t* __restrict__ Bl,
    int M, int N, int K, int bn_off, float* __restrict__ C,
    const float* __restrict__ lambda,
    ushort_t* __restrict__ qhp, ushort_t* __restrict__ qlp,
    ushort_t* __restrict__ khp, ushort_t* __restrict__ klp,
    ushort_t* __restrict__ vtp) {
  __shared__ ushort_t As[COMP + 1][128 * 64];
  __shared__ ushort_t Bs[COMP + 1][128 * 64];

  const int tid = threadIdx.x;
  const int w = tid >> 6;
  const int lane = tid & 63;
  const int lcol = lane & 15;
  const int g = lane >> 4;
  const int bm = SLICE ? ((blockIdx.y >> 1) * Tn + (blockIdx.y & 1) * 128)
                       : (blockIdx.y * 128);
  const int bn = blockIdx.x * 128 + bn_off;
  const int wr = (w >> 1) * 64;
  const int wc = (w & 1) * 64;
  const int srow = tid >> 3;
  const int sslot = tid & 7;

  f32x4 acc[4][4];
  #pragma unroll
  for (int m = 0; m < 4; ++m)
    #pragma unroll
    for (int n = 0; n < 4; ++n)
      acc[m][n] = (f32x4){0.f, 0.f, 0.f, 0.f};

  for (int k0 = 0; k0 < K; k0 += 64) {
    __syncthreads();
    #pragma unroll
    for (int i = 0; i < 4; ++i) {
      const int row = i * 32 + srow;
      const int kslot = sslot ^ (row & 7);
      const size_t ga = (size_t)(bm + row) * K + k0 + kslot * 8;
      const size_t gb = (size_t)(bn + row) * K + k0 + kslot * 8;
      const size_t ldst = (size_t)(i * 256 + tid) * 16;
      GLOAD_LDS16(Ah + ga, (char*)As[0] + ldst);
      GLOAD_LDS16(Bh + gb, (char*)Bs[0] + ldst);
      if (COMP) {
        GLOAD_LDS16(Al + ga, (char*)As[COMP] + ldst);
        GLOAD_LDS16(Bl + gb, (char*)Bs[COMP] + ldst);
      }
    }
    __syncthreads();
    #pragma unroll
    for (int kk = 0; kk < 2; ++kk) {
      short8v a0[4], b0[4], a1[4], b1[4];
      #pragma unroll
      for (int m = 0; m < 4; ++m) {
        int row = wr + m * 16 + lcol;
        int off = row * 128 + (((kk * 4 + g) ^ (row & 7)) << 4);
        a0[m] = *reinterpret_cast<const short8v*>((const char*)As[0] + off);
        if (COMP) a1[m] = *reinterpret_cast<const short8v*>((const char*)As[COMP] + off);
      }
      #pragma unroll
      for (int n = 0; n < 4; ++n) {
        int row = wc + n * 16 + lcol;
        int off = row * 128 + (((kk * 4 + g) ^ (row & 7)) << 4);
        b0[n] = *reinterpret_cast<const short8v*>((const char*)Bs[0] + off);
        if (COMP) b1[n] = *reinterpret_cast<const short8v*>((const char*)Bs[COMP] + off);
      }
      #pragma unroll
      for (int m = 0; m < 4; ++m)
        #pragma unroll
        for (int n = 0; n < 4; ++n) {
          acc[m][n] = __builtin_amdgcn_mfma_f32_16x16x32_bf16(a0[m], b0[n], acc[m][n], 0, 0, 0);
          if (COMP) {
            acc[m][n] = __builtin_amdgcn_mfma_f32_16x16x32_bf16(a0[m], b1[n], acc[m][n], 0, 0, 0);
            acc[m][n] = __builtin_amdgcn_mfma_f32_16x16x32_bf16(a1[m], b0[n], acc[m][n], 0, 0, 0);
          }
        }
    }
  }

  if (MODE == 0) {
    #pragma unroll
    for (int m = 0; m < 4; ++m) {
      const int rowm = bm + wr + m * 16 + g * 4;
      #pragma unroll
      for (int n = 0; n < 4; ++n) {
        const int col = bn + wc + n * 16 + lcol;
        #pragma unroll
        for (int j = 0; j < 4; ++j)
          C[(size_t)(rowm + j) * N + col] = acc[m][n][j];
      }
    }
  } else {
    const int seg = bn / Cn;                  // uniform (768 % 128 == 0)
    const int nloc_base = bn - seg * Cn + wc;
    #pragma unroll
    for (int m = 0; m < 4; ++m) {
      const int mg = bm + wr + m * 16 + g * 4;
      const int bidx = mg >> 11;
      const int tbase = mg & (Tn - 1);
      float lgt[4];
      if (seg == 0) {
        #pragma unroll
        for (int j = 0; j < 4; ++j) lgt[j] = logf((float)(tbase + j) + 1.0f);
      }
      #pragma unroll
      for (int n = 0; n < 4; ++n) {
        const int nloc = nloc_base + n * 16 + lcol;
        const int h = nloc >> 6;
        const int d = nloc & 63;
        const size_t bhh = (size_t)(bidx * Hn + h);
        if (seg == 0) {
          const float lam = lambda[h];
          #pragma unroll
          for (int j = 0; j < 4; ++j) {
            float val = acc[m][n][j] * (0.125f * (1.0f + lam * lgt[j]));
            unsigned short hi = f2bf(val);
            unsigned short lo = f2bf(val - bf2f(hi));
            size_t idx = (bhh * Tn + tbase + j) * 64 + d;
            qhp[idx] = hi; qlp[idx] = lo;
          }
        } else if (seg == 1) {
          #pragma unroll
          for (int j = 0; j < 4; ++j) {
            float val = acc[m][n][j];
            unsigned short hi = f2bf(val);
            unsigned short lo = f2bf(val - bf2f(hi));
            size_t idx = (bhh * Tn + tbase + j) * 64 + d;
            khp[idx] = hi; klp[idx] = lo;
          }
        } else {
          #pragma unroll
          for (int j = 0; j < 4; ++j)
            vtp[(bhh * 64 + d) * Tn + tbase + j] = f2bf(acc[m][n][j]);
        }
      }
    }
  }
}

// ---------------- MFMA flash-style relu-attention, 128 q-rows/block --------------
// 2-phase double-buffered K/V staging.  Precision scoping:
//   qt==0 : q+k compensated QK^T (6 MFMA)  [knife-edge rows t<128]
//   qt==1 : q compensated (4 MFMA)         [rows 128..255]
//   qt>=2 : plain bf16 (2 MFMA)            [den large, error ~|v|*eps/den]
__global__ __launch_bounds__(256) void attn_mfma(
    const ushort_t* __restrict__ qh, const ushort_t* __restrict__ ql,
    const ushort_t* __restrict__ kh, const ushort_t* __restrict__ kl,
    const ushort_t* __restrict__ vt, const float* __restrict__ attn_mask,
    ushort_t* __restrict__ ao) {
  static const int QT1[16] = {15,13,11,9,7,5,3,1,14,12,10,8,6,4,2,0};
  static const int QT2[16] = {7,9,10,11,12,13,14,15,0,1,2,3,4,5,6,8};
  const int cc_ = blockIdx.x & 255;
  const int rr_ = blockIdx.x >> 8;           // 0..2
  const int bh  = (cc_ >> 4) + (rr_ << 4);   // 0..47
  const int ii_ = cc_ & 15;
  const int qt  = (rr_ == 0) ? ii_ : (rr_ == 1 ? QT1[ii_] : QT2[ii_]);
  const int b = bh / Hn, h = bh % Hn;
  const int tid = threadIdx.x;
  const int w = tid >> 6, lane = tid & 63, lcol = lane & 15, g = lane >> 4;

  const bool compq = (qt <= 1);
  const bool compk = (qt == 0);

  __shared__ ushort_t Kh_lds[2][64 * 64];
  __shared__ ushort_t V_lds[2][64 * 64];
  __shared__ ushort_t P_lds[4][2][16][72];

  // Q fragments for the wave's two 16-row groups
  short8v qfh[2][2], qfl[2][2];
  #pragma unroll
  for (int m = 0; m < 2; ++m) {
    const size_t qoff = ((size_t)bh * Tn + qt * 128 + w * 32 + m * 16 + lcol) * 64;
    qfh[m][0] = *reinterpret_cast<const short8v*>(qh + qoff + g * 8);
    qfh[m][1] = *reinterpret_cast<const short8v*>(qh + qoff + 32 + g * 8);
    if (compq) {
      qfl[m][0] = *reinterpret_cast<const short8v*>(ql + qoff + g * 8);
      qfl[m][1] = *reinterpret_cast<const short8v*>(ql + qoff + 32 + g * 8);
    }
  }

  f32x4 o[2][4];
  float dsum[2][4];
  #pragma unroll
  for (int m = 0; m < 2; ++m) {
    #pragma unroll
    for (int dt = 0; dt < 4; ++dt) o[m][dt] = (f32x4){0.f, 0.f, 0.f, 0.f};
    #pragma unroll
    for (int r = 0; r < 4; ++r) dsum[m][r] = 0.f;
  }

  float mv_cur[4], mv_nxt[4];

  auto STAGE = [&](int kt, int d) {
    const ushort_t* ks = kh + ((size_t)bh * Tn + kt * 64) * 64;
    const ushort_t* vs = vt + (size_t)bh * 64 * Tn + kt * 64;
    #pragma unroll
    for (int it = 0; it < 2; ++it) {
      const int s = it * 256 + tid;
      const int row = s >> 3, sslot = s & 7;
      const int swz = (sslot ^ (row & 7)) * 8;
      GLOAD_LDS16(ks + row * 64 + swz, (char*)Kh_lds[d] + (size_t)s * 16);
      GLOAD_LDS16(vs + (size_t)row * Tn + swz, (char*)V_lds[d] + (size_t)s * 16);
    }
  };
  auto STAGE_KL = [&](int kt) {   // qt==0 only: Kl parked in Kh_lds[1]
    const ushort_t* ls = kl + ((size_t)bh * Tn + kt * 64) * 64;
    #pragma unroll
    for (int it = 0; it < 2; ++it) {
      const int s = it * 256 + tid;
      const int row = s >> 3, sslot = s & 7;
      const int swz = (sslot ^ (row & 7)) * 8;
      GLOAD_LDS16(ls + row * 64 + swz, (char*)Kh_lds[1] + (size_t)s * 16);
    }
  };
  auto MLOAD = [&](int kt, float* mv) {
    #pragma unroll
    for (int c = 0; c < 4; ++c)
      mv[c] = attn_mask[b * Tn + kt * 64 + c * 16 + lcol];
  };

  auto COMPUTE = [&](int kt, int d, bool cq, bool ck) {
    bool active[2];
    #pragma unroll
    for (int m = 0; m < 2; ++m) {
      const int qg = qt * 128 + w * 32 + m * 16;
      const bool skip = (kt * 64 > qg + 15);
      active[m] = !skip;
      if (skip) continue;
      const bool diag = (kt * 64 + 63 > qg);
      #pragma unroll
      for (int c = 0; c < 4; ++c) {
        const int row = c * 16 + lcol;
        const int roff = row * 128;
        const int s0 = (g ^ (row & 7)) << 4;
        const int s1 = ((4 + g) ^ (row & 7)) << 4;
        short8v kf0h = *reinterpret_cast<const short8v*>((const char*)Kh_lds[d] + roff + s0);
        short8v kf1h = *reinterpret_cast<const short8v*>((const char*)Kh_lds[d] + roff + s1);
        f32x4 s = (f32x4){0.f, 0.f, 0.f, 0.f};
        __builtin_amdgcn_s_setprio(1);
        s = __builtin_amdgcn_mfma_f32_16x16x32_bf16(qfh[m][0], kf0h, s, 0, 0, 0);
        s = __builtin_amdgcn_mfma_f32_16x16x32_bf16(qfh[m][1], kf1h, s, 0, 0, 0);
        if (cq) {
          s = __builtin_amdgcn_mfma_f32_16x16x32_bf16(qfl[m][0], kf0h, s, 0, 0, 0);
          s = __builtin_amdgcn_mfma_f32_16x16x32_bf16(qfl[m][1], kf1h, s, 0, 0, 0);
        }
        if (ck) {
          short8v kf0l = *reinterpret_cast<const short8v*>((const char*)Kh_lds[1] + roff + s0);
          short8v kf1l = *reinterpret_cast<const short8v*>((const char*)Kh_lds[1] + roff + s1);
          s = __builtin_amdgcn_mfma_f32_16x16x32_bf16(qfh[m][0], kf0l, s, 0, 0, 0);
          s = __builtin_amdgcn_mfma_f32_16x16x32_bf16(qfh[m][1], kf1l, s, 0, 0, 0);
        }
        __builtin_amdgcn_s_setprio(0);
        const float mval = mv_cur[c];
        float sv[4];
        #pragma unroll
        for (int r = 0; r < 4; ++r) {
          float v = fmaxf(s[r], 0.f) * mval;
          if (diag) {
            const int kr = kt * 64 + row;
            const int qr = qg + g * 4 + r;
            v = (kr <= qr) ? v : 0.f;
          }
          sv[r] = v;
        }
        const unsigned p01 = cvt_pk_bf16(sv[0], sv[1]);
        const unsigned p23 = cvt_pk_bf16(sv[2], sv[3]);
        P_lds[w][m][g * 4 + 0][row] = (ushort_t)p01;
        P_lds[w][m][g * 4 + 1][row] = (ushort_t)(p01 >> 16);
        P_lds[w][m][g * 4 + 2][row] = (ushort_t)p23;
        P_lds[w][m][g * 4 + 3][row] = (ushort_t)(p23 >> 16);
        dsum[m][0] += u2f(p01 << 16);
        dsum[m][1] += u2f(p01 & 0xFFFF0000u);
        dsum[m][2] += u2f(p23 << 16);
        dsum[m][3] += u2f(p23 & 0xFFFF0000u);
      }
    }

    // PV — no extra barrier: P region is wave-private, V staged this tile.
    short8v pf[2][2];
    #pragma unroll
    for (int m = 0; m < 2; ++m)
      if (active[m]) {
        pf[m][0] = *reinterpret_cast<const short8v*>(&P_lds[w][m][lcol][g * 8]);
        pf[m][1] = *reinterpret_cast<const short8v*>(&P_lds[w][m][lcol][32 + g * 8]);
      }
    #pragma unroll
    for (int dt = 0; dt < 4; ++dt) {
      const int vrow = dt * 16 + lcol;
      const int vro = vrow * 128;
      short8v vf0 = *reinterpret_cast<const short8v*>(
          (const char*)V_lds[d] + vro + ((g ^ (vrow & 7)) << 4));
      short8v vf1 = *reinterpret_cast<const short8v*>(
          (const char*)V_lds[d] + vro + (((4 + g) ^ (vrow & 7)) << 4));
      __builtin_amdgcn_s_setprio(1);
      #pragma unroll
      for (int m = 0; m < 2; ++m)
        if (active[m]) {
          o[m][dt] = __builtin_amdgcn_mfma_f32_16x16x32_bf16(pf[m][0], vf0, o[m][dt], 0, 0, 0);
          o[m][dt] = __builtin_amdgcn_mfma_f32_16x16x32_bf16(pf[m][1], vf1, o[m][dt], 0, 0, 0);
        }
      __builtin_amdgcn_s_setprio(0);
    }
  };

  if (qt == 0) {
    // 2 tiles, sequential, full q+k compensation (knife-edge rows t<128)
    for (int kt = 0; kt < 2; ++kt) {
      STAGE(kt, 0);
      STAGE_KL(kt);
      MLOAD(kt, mv_cur);
      __syncthreads();
      COMPUTE(kt, 0, true, true);
      __syncthreads();
    }
  } else {
    const int ntiles = 2 * qt + 2;
    MLOAD(0, mv_cur);
    STAGE(0, 0);
    __syncthreads();
    for (int kt = 0; kt < ntiles; ++kt) {
      const int d = kt & 1;
      if (kt + 1 < ntiles) { STAGE(kt + 1, d ^ 1); MLOAD(kt + 1, mv_nxt); }
      COMPUTE(kt, d, compq, false);
      __syncthreads();
      #pragma unroll
      for (int c = 0; c < 4; ++c) mv_cur[c] = mv_nxt[c];
    }
  }

  #pragma unroll
  for (int m = 0; m < 2; ++m) {
    float inv[4];
    #pragma unroll
    for (int r = 0; r < 4; ++r) {
      float d = dsum[m][r];
      d += __shfl_xor(d, 1); d += __shfl_xor(d, 2);
      d += __shfl_xor(d, 4); d += __shfl_xor(d, 8);
      inv[r] = 1.0f / (d + 1e-9f);
    }
    ushort_t* ob = ao + ((size_t)b * Tn + qt * 128 + w * 32 + m * 16) * Cn + h * 64;
    #pragma unroll
    for (int dt = 0; dt < 4; ++dt)
      #pragma unroll
      for (int r = 0; r < 4; ++r)
        ob[(size_t)(g * 4 + r) * Cn + dt * 16 + lcol] = f2bf(o[m][dt][r] * inv[r]);
  }
}

extern "C" void kernel_launch(void* const* d_in, const int* in_sizes, int n_in,
                              void* d_out, int out_size, void* d_ws, size_t ws_size,
                              hipStream_t stream) {
  const float* x         = (const float*)d_in[0];
  const float* attn_mask = (const float*)d_in[1];
  const float* lambda    = (const float*)d_in[2];
  const float* W_attn    = (const float*)d_in[3];
  const float* W_proj    = (const float*)d_in[4];
  float* out = (float*)d_out;

  const size_t nBTC = (size_t)Bn * Tn * Cn;        // 6.29M
  const size_t nW1  = (size_t)Cn * 3 * Cn;         // 1.77M
  const size_t nW2  = (size_t)Cn * Cn;             // 0.59M
  ushort_t* xh  = (ushort_t*)d_ws;
  ushort_t* xl  = xh + nBTC;
  ushort_t* WhT = xl + nBTC;
  ushort_t* WlT = WhT + nW1;
  ushort_t* WpT = WlT + nW1;
  ushort_t* qh  = WpT + nW2;
  ushort_t* ql  = qh + nBTC;
  ushort_t* kh  = ql + nBTC;
  ushort_t* kl  = kh + nBTC;
  ushort_t* vt  = kl + nBTC;
  ushort_t* ao  = xh;   // xh dead after gemm1; reuse for attention output

  dim3 blk(256);

  conv_x_split<<<dim3((unsigned)(nBTC / 4 / 256)), blk, 0, stream>>>(
      x, xh, xl, (int)(nBTC / 4));
  conv_wT<1><<<dim3(36, 12), blk, 0, stream>>>(W_attn, WhT, WlT, Cn, 3 * Cn);
  conv_wT<0><<<dim3(12, 12), blk, 0, stream>>>(W_proj, WpT, nullptr, Cn, Cn);

  // full qkv: plain bf16 GEMM (q,k hi/lo from fp32 acc; v transposed)
  gemm_bf16<0, 1, 0><<<dim3(18, 64), blk, 0, stream>>>(
      xh, nullptr, WhT, nullptr, Bn * Tn, 3 * Cn, Cn, 0, nullptr, lambda,
      qh, ql, kh, kl, vt);
  // accurate overwrite slice: rows t<256 of q,k (compensated, fp32 quality)
  gemm_bf16<1, 1, 1><<<dim3(12, 8), blk, 0, stream>>>(
      xh, xl, WhT, WlT, Bn * Tn, 3 * Cn, Cn, 0, nullptr, lambda,
      qh, ql, kh, kl, vt);

  attn_mfma<<<dim3(768), blk, 0, stream>>>(
      qh, ql, kh, kl, vt, attn_mask, ao);

  gemm_bf16<0, 0, 0><<<dim3(6, 64), blk, 0, stream>>>(
      ao, nullptr, WpT, nullptr, Bn * Tn, Cn, Cn, 0, out, nullptr,
      nullptr, nullptr, nullptr, nullptr, nullptr);
}